// Round 16
// baseline (143.767 us; speedup 1.0000x reference)
//
#include <hip/hip_runtime.h>
#include <math.h>

#define N_NODES 100000
#define N_HIGH  20000
#define N_EDGES 200000
#define D       128
#define HEADS   4
#define EPSF    1e-16f

typedef __attribute__((ext_vector_type(8))) short bf16x8;
typedef __attribute__((ext_vector_type(4))) float f32x4;
typedef unsigned short ushort_t;
typedef unsigned int uint_t;

__device__ __forceinline__ ushort_t bf16_rn(float f) {
  uint_t u = __float_as_uint(f);
  u = u + 0x7FFFu + ((u >> 16) & 1u);   // round-to-nearest-even
  return (ushort_t)(u >> 16);
}
__device__ __forceinline__ uint_t pack_bf2(float x, float y) {
  return (uint_t)bf16_rn(x) | ((uint_t)bf16_rn(y) << 16);
}
__device__ __forceinline__ float readlane_f(float v, int q) {
  return __uint_as_float(__builtin_amdgcn_readlane(__float_as_uint(v), q));
}

// ---------------- workspace layout (bytes) ----------------
constexpr size_t OFF_VSRC = 0;                       // 512 f
constexpr size_t OFF_VDST = OFF_VSRC + 512 * 4;      // 512 f
constexpr size_t OFF_P    = OFF_VDST + 512 * 4;      // Pt bf16 [128][512] (region 256 KB)
constexpr size_t OFF_APK  = OFF_P    + 65536 * 4;    // a_pack float4[200000] = 3.2 MB
constexpr size_t OFF_CNT  = OFF_APK  + 800000 * 4;   // 20000 i
constexpr size_t OFF_OFFS = OFF_CNT  + 20000 * 4;    // 20001 i (padded)
constexpr size_t OFF_FILL = OFF_OFFS + 20004 * 4;    // (unused)
constexpr size_t OFF_SORT = OFF_FILL + 20000 * 4;    // 200000 int2 = 1.6 MB
constexpr size_t OFF_G    = OFF_SORT + 200000 * 8;   // (unused)
constexpr size_t OFF_NFB  = OFF_G    + 20000 * 512 * 2;  // nf bf16 [100000][128] = 25.6 MB
constexpr size_t OFF_AHS  = OFF_NFB  + (size_t)100000 * 128 * 2; // ahsum float4[20000] = 320 KB

// -------- fused: vecs (+zero cnt/ahsum) | P  --------
__global__ __launch_bounds__(256) void k_vp(
    const float* __restrict__ Wsrc, const float* __restrict__ Wdst,
    const float* __restrict__ att_src, const float* __restrict__ att_dst,
    const float* __restrict__ Whigh,
    float* __restrict__ v_src, float* __restrict__ v_dst,
    int* __restrict__ cnt, float4* __restrict__ ahsum,
    ushort_t* __restrict__ Pt) {
  __shared__ float red[128];
  if (blockIdx.x < 256) {
    int gid = blockIdx.x * 256 + threadIdx.x;
    if (gid < N_HIGH) {
      cnt[gid] = 0;
      ahsum[gid] = make_float4(0.f, 0.f, 0.f, 0.f);
    }

    int W = blockIdx.x * 4 + (threadIdx.x >> 6);   // 0..1023
    int lane = threadIdx.x & 63;
    int which = W >> 9;
    int idx = W & 511;
    int k = idx >> 2, h = idx & 3;
    const float* wrow = (which ? Wdst : Wsrc) + k * (HEADS * D) + h * D;
    const float* arow = (which ? att_src : att_dst) + h * D;
    float2 wv = ((const float2*)wrow)[lane];
    float2 av = ((const float2*)arow)[lane];
    float s = wv.x * av.x + wv.y * av.y;
#pragma unroll
    for (int o = 32; o; o >>= 1) s += __shfl_xor(s, o);
    if (lane == 0) {
      if (which) v_src[k * HEADS + h] = s;
      else       v_dst[k * HEADS + h] = s;
    }
  } else {
    int hk = blockIdx.x - 256;      // 0..511: (h,col)
    int h = hk >> 7, col = hk & 127;
    int d = threadIdx.x & 127, half = threadIdx.x >> 7;
    const float* ws = Wsrc + col * (HEADS * D) + h * D + half * 64;
    const float* wh = Whigh + (size_t)(half * 64) * D + d;
    float s = 0.f;
#pragma unroll 8
    for (int m = 0; m < 64; ++m) s += ws[m] * wh[(size_t)m * D];
    if (half) red[d] = s;
    __syncthreads();
    if (!half) {
      int kp = (col >> 1) * 8 + h * 2 + (col & 1);
      Pt[(size_t)d * 512 + kp] = bf16_rn(0.25f * (s + red[d]));
    }
  }
}

// -------- fused: nodeproj (+ nf->bf16 copy) | hist --------
// a_pack[2n] = a_srcn(n), a_pack[2n+1] = a_dstn(n)
#define NP_BLOCKS 1563            // ceil(100000/64)
#define H_BLOCKS  782             // ceil(200000/256)
__global__ __launch_bounds__(256) void k_nodehist(
    const float* __restrict__ nf,
    const float* __restrict__ v_src, const float* __restrict__ v_dst,
    float4* __restrict__ a_pack,
    const int* __restrict__ dst, int* __restrict__ cnt,
    ushort_t* __restrict__ nfb) {
  __shared__ float nfT[128 * 65];
  __shared__ float4 vsf4[128];
  __shared__ float4 vdf4[128];
  __shared__ float part[8][4][64];
  int t = threadIdx.x;
  if (blockIdx.x >= NP_BLOCKS) {
    int e = (blockIdx.x - NP_BLOCKS) * 256 + t;
    if (e < N_EDGES) atomicAdd(&cnt[dst[e]], 1);
    return;
  }
  int n0 = blockIdx.x * 64;

  if (t < 128) vsf4[t] = ((const float4*)v_src)[t];
  else vdf4[t - 128] = ((const float4*)v_dst)[t - 128];

  const float4* nf4 = (const float4*)nf;
#pragma unroll
  for (int j = 0; j < 8; ++j) {
    int f4 = j * 256 + t;
    int r = f4 >> 5, c4 = f4 & 31;
    int n = n0 + r;
    if (n > N_NODES - 1) n = N_NODES - 1;   // clamped dup rows write same bytes
    float4 g = nf4[(size_t)n * 32 + c4];
    nfT[(c4 * 4 + 0) * 65 + r] = g.x;
    nfT[(c4 * 4 + 1) * 65 + r] = g.y;
    nfT[(c4 * 4 + 2) * 65 + r] = g.z;
    nfT[(c4 * 4 + 3) * 65 + r] = g.w;
    ushort4 hb;
    hb.x = bf16_rn(g.x); hb.y = bf16_rn(g.y);
    hb.z = bf16_rn(g.z); hb.w = bf16_rn(g.w);
    ((ushort4*)nfb)[(size_t)n * 32 + c4] = hb;
  }
  __syncthreads();

  int l = t & 63, w = t >> 6;
  float as[4] = {0.f, 0.f, 0.f, 0.f};
  float ad[4] = {0.f, 0.f, 0.f, 0.f};
#pragma unroll 8
  for (int kk = 0; kk < 32; ++kk) {
    int k = w * 32 + kk;
    float x = nfT[k * 65 + l];
    float4 s4 = vsf4[k];
    float4 d4 = vdf4[k];
    as[0] += x * s4.x; as[1] += x * s4.y; as[2] += x * s4.z; as[3] += x * s4.w;
    ad[0] += x * d4.x; ad[1] += x * d4.y; ad[2] += x * d4.z; ad[3] += x * d4.w;
  }
#pragma unroll
  for (int v = 0; v < 4; ++v) {
    part[v][w][l] = as[v];
    part[v + 4][w][l] = ad[v];
  }
  __syncthreads();

  if (t < 64) {
    int ll = t;
    if (n0 + ll < N_NODES) {
      float4 o;
      o.x = part[0][0][ll] + part[0][1][ll] + part[0][2][ll] + part[0][3][ll];
      o.y = part[1][0][ll] + part[1][1][ll] + part[1][2][ll] + part[1][3][ll];
      o.z = part[2][0][ll] + part[2][1][ll] + part[2][2][ll] + part[2][3][ll];
      o.w = part[3][0][ll] + part[3][1][ll] + part[3][2][ll] + part[3][3][ll];
      a_pack[(size_t)(n0 + ll) * 2] = o;
    }
  } else if (t < 128) {
    int ll = t - 64;
    if (n0 + ll < N_NODES) {
      float4 o;
      o.x = part[4][0][ll] + part[4][1][ll] + part[4][2][ll] + part[4][3][ll];
      o.y = part[5][0][ll] + part[5][1][ll] + part[5][2][ll] + part[5][3][ll];
      o.z = part[6][0][ll] + part[6][1][ll] + part[6][2][ll] + part[6][3][ll];
      o.w = part[7][0][ll] + part[7][1][ll] + part[7][2][ll] + part[7][3][ll];
      a_pack[(size_t)(n0 + ll) * 2 + 1] = o;
    }
  }
}

// exclusive scan of cnt[20000] -> offs[20001]; shfl-based, ONE barrier
#define SCAN_PER 20
__global__ __launch_bounds__(1024) void k_scan(
    const int* __restrict__ cnt, int* __restrict__ offs) {
  __shared__ int wsum[16];
  int t = threadIdx.x;
  int lane = t & 63, wv = t >> 6;
  int base = t * SCAN_PER;
  int loc[SCAN_PER];
  int s = 0;
#pragma unroll
  for (int i = 0; i < SCAN_PER; ++i) {
    int idx = base + i;
    loc[i] = (idx < N_HIGH) ? cnt[idx] : 0;
    s += loc[i];
  }
  // inclusive wave scan of s
  int tot = s;
#pragma unroll
  for (int o = 1; o < 64; o <<= 1) {
    int v = __shfl_up(tot, o);
    if (lane >= o) tot += v;
  }
  if (lane == 63) wsum[wv] = tot;
  __syncthreads();
  int wpre = 0;
  for (int i = 0; i < 16; ++i) wpre += (i < wv) ? wsum[i] : 0;
  int run = wpre + tot - s;   // exclusive prefix for this thread's chunk
#pragma unroll
  for (int i = 0; i < SCAN_PER; ++i) {
    int idx = base + i;
    if (idx < N_HIGH) {
      offs[idx] = run;
      run += loc[i];
    }
  }
  if (t == 1023) offs[N_HIGH] = wpre + tot;
}

// counting-sort scatter + per-hyperedge a_srcn sum via float atomics
__global__ void k_scatter(const int* __restrict__ dst, const int* __restrict__ src,
                          const int* __restrict__ offs,
                          int* __restrict__ cnt, int2* __restrict__ sorted,
                          const float4* __restrict__ a_pack,
                          float* __restrict__ ahsum) {
  int e = blockIdx.x * blockDim.x + threadIdx.x;
  if (e < N_EDGES) {
    int d = dst[e];
    int sn = src[e];
    int pos = offs[d] + (atomicSub(&cnt[d], 1) - 1);
    sorted[pos] = make_int2(e, sn);
    float4 a = a_pack[(size_t)sn * 2];
    atomicAdd(&ahsum[(size_t)d * 4 + 0], a.x);
    atomicAdd(&ahsum[(size_t)d * 4 + 1], a.y);
    atomicAdd(&ahsum[(size_t)d * 4 + 2], a.z);
    atomicAdd(&ahsum[(size_t)d * 4 + 3], a.w);
  }
}

// -------- fused main+gemm: 512 thr = 8 waves; 16 hyperedges (2/wave) --------
// ah comes precomputed from ahsum (scatter) -> no a_srcn gather, no first
// shuffle chain. Branch-free unrolled gather loop as before.
#define RS 520   // padded LDS row stride (ushorts): 2-way-free ds_read_b128
__global__ __launch_bounds__(512) void k_mg(
    const ushort_t* __restrict__ nfb,
    const float4* __restrict__ a_pack,
    const float4* __restrict__ ahsum,
    const int* __restrict__ offs, const int2* __restrict__ sorted,
    const ushort_t* __restrict__ Pt, const float* __restrict__ b,
    float* __restrict__ alpha_out, float* __restrict__ out) {
  __shared__ ushort_t Gl[16 * RS];          // 16.3 KB
  int t = threadIdx.x;
  int w = t >> 6, lane = t & 63;
  int j0 = blockIdx.x * 16;
  int rowA = w * 2, rowB = rowA + 1;
  int jA = j0 + rowA;
  int oA0 = offs[jA], oA1 = offs[jA + 1], oB1 = offs[jA + 2];
  int oB0 = oA1;
  int degA = oA1 - oA0, degB = oB1 - oB0;

  float2 accA[4], accB[4];
#pragma unroll
  for (int h = 0; h < 4; ++h) {
    accA[h] = make_float2(0.f, 0.f);
    accB[h] = make_float2(0.f, 0.f);
  }

  if (degA <= 64 && degB <= 64) {
    // ---- interleaved fast path (handles deg==0 via act masks) ----
    bool actA = lane < degA, actB = lane < degB;
    int idxA = min(oA0 + (actA ? lane : 0), N_EDGES - 1);
    int idxB = min(oB0 + (actB ? lane : 0), N_EDGES - 1);
    int2 esA = sorted[idxA];
    int2 esB = sorted[idxB];
    int eA = esA.x, srA = esA.y;
    int eB = esB.x, srB = esB.y;
    float4 z4 = make_float4(0.f, 0.f, 0.f, 0.f);
    float4 adA = z4, adB = z4;
    if (actA) adA = a_pack[(size_t)srA * 2 + 1];
    if (actB) adB = a_pack[(size_t)srB * 2 + 1];
    float4 ahA4 = ahsum[jA];
    float4 ahB4 = ahsum[jA + 1];
    float invA = 1.0f / (float)max(degA, 1);
    float invB = 1.0f / (float)max(degB, 1);

    float exA[4], exB[4];
    {
      float pA0 = ahA4.x * invA + adA.x, pA1 = ahA4.y * invA + adA.y;
      float pA2 = ahA4.z * invA + adA.z, pA3 = ahA4.w * invA + adA.w;
      float pB0 = ahB4.x * invB + adB.x, pB1 = ahB4.y * invB + adB.y;
      float pB2 = ahB4.z * invB + adB.z, pB3 = ahB4.w * invB + adB.w;
      pA0 = pA0 >= 0.f ? pA0 : 0.2f * pA0;
      pA1 = pA1 >= 0.f ? pA1 : 0.2f * pA1;
      pA2 = pA2 >= 0.f ? pA2 : 0.2f * pA2;
      pA3 = pA3 >= 0.f ? pA3 : 0.2f * pA3;
      pB0 = pB0 >= 0.f ? pB0 : 0.2f * pB0;
      pB1 = pB1 >= 0.f ? pB1 : 0.2f * pB1;
      pB2 = pB2 >= 0.f ? pB2 : 0.2f * pB2;
      pB3 = pB3 >= 0.f ? pB3 : 0.2f * pB3;
      exA[0] = actA ? expf(pA0) : 0.f;
      exA[1] = actA ? expf(pA1) : 0.f;
      exA[2] = actA ? expf(pA2) : 0.f;
      exA[3] = actA ? expf(pA3) : 0.f;
      exB[0] = actB ? expf(pB0) : 0.f;
      exB[1] = actB ? expf(pB1) : 0.f;
      exB[2] = actB ? expf(pB2) : 0.f;
      exB[3] = actB ? expf(pB3) : 0.f;
    }
    float seA[4] = {exA[0], exA[1], exA[2], exA[3]};
    float seB[4] = {exB[0], exB[1], exB[2], exB[3]};
#pragma unroll
    for (int o = 32; o; o >>= 1)
#pragma unroll
      for (int h = 0; h < 4; ++h) {
        seA[h] += __shfl_xor(seA[h], o);
        seB[h] += __shfl_xor(seB[h], o);
      }
    float alA[4], alB[4];
#pragma unroll
    for (int h = 0; h < 4; ++h) {
      alA[h] = exA[h] / (seA[h] + EPSF);
      alB[h] = exB[h] / (seB[h] + EPSF);
    }
    if (actA)
      ((float4*)alpha_out)[eA] = make_float4(alA[0], alA[1], alA[2], alA[3]);
    if (actB)
      ((float4*)alpha_out)[eB] = make_float4(alB[0], alB[1], alB[2], alB[3]);

    // branch-free fused gather loop: both hyperedges every iteration
    const uint_t* __restrict__ nfbu = (const uint_t*)nfb;
    int dmax = max(degA, degB);
#pragma unroll 8
    for (int q = 0; q < dmax; ++q) {
      int sqA = __builtin_amdgcn_readlane(srA, q);
      int sqB = __builtin_amdgcn_readlane(srB, q);
      uint_t xwA = nfbu[(size_t)sqA * 64 + lane];
      uint_t xwB = nfbu[(size_t)sqB * 64 + lane];
      float a0 = readlane_f(alA[0], q);
      float a1 = readlane_f(alA[1], q);
      float a2 = readlane_f(alA[2], q);
      float a3 = readlane_f(alA[3], q);
      float b0 = readlane_f(alB[0], q);
      float b1 = readlane_f(alB[1], q);
      float b2 = readlane_f(alB[2], q);
      float b3 = readlane_f(alB[3], q);
      float xAx = __uint_as_float(xwA << 16);
      float xAy = __uint_as_float(xwA & 0xFFFF0000u);
      float xBx = __uint_as_float(xwB << 16);
      float xBy = __uint_as_float(xwB & 0xFFFF0000u);
      accA[0].x += a0 * xAx; accA[0].y += a0 * xAy;
      accA[1].x += a1 * xAx; accA[1].y += a1 * xAy;
      accA[2].x += a2 * xAx; accA[2].y += a2 * xAy;
      accA[3].x += a3 * xAx; accA[3].y += a3 * xAy;
      accB[0].x += b0 * xBx; accB[0].y += b0 * xBy;
      accB[1].x += b1 * xBx; accB[1].y += b1 * xBy;
      accB[2].x += b2 * xBx; accB[2].y += b2 * xBy;
      accB[3].x += b3 * xBx; accB[3].y += b3 * xBy;
    }
  } else {
    // ---- rare fallback: general chunked path, works for any deg ----
    for (int pick = 0; pick < 2; ++pick) {
      int o0 = pick ? oB0 : oA0;
      int deg = pick ? degB : degA;
      int jj = jA + pick;
      float2* acc = pick ? accB : accA;

      float4 ah4 = ahsum[jj];
      float invdeg = 1.0f / (float)max(deg, 1);
      float ah[4] = {ah4.x * invdeg, ah4.y * invdeg, ah4.z * invdeg, ah4.w * invdeg};

      float se[4] = {0.f, 0.f, 0.f, 0.f};
      for (int i = lane; i < deg; i += 64) {
        int2 es = sorted[o0 + i];
        float4 a = a_pack[(size_t)es.y * 2 + 1];
        float p[4] = {ah[0] + a.x, ah[1] + a.y, ah[2] + a.z, ah[3] + a.w};
#pragma unroll
        for (int h = 0; h < 4; ++h) {
          float pp = p[h] >= 0.f ? p[h] : 0.2f * p[h];
          se[h] += expf(pp);
        }
      }
#pragma unroll
      for (int o = 32; o; o >>= 1)
#pragma unroll
        for (int h = 0; h < 4; ++h) se[h] += __shfl_xor(se[h], o);
      float inv[4];
#pragma unroll
      for (int h = 0; h < 4; ++h) inv[h] = 1.0f / (se[h] + EPSF);

      for (int c0 = 0; c0 < deg; c0 += 64) {
        int i = c0 + lane;
        float al[4] = {0.f, 0.f, 0.f, 0.f};
        int sreg = 0;
        if (i < deg) {
          int2 es = sorted[o0 + i];
          sreg = es.y;
          float4 a = a_pack[(size_t)sreg * 2 + 1];
          float p[4] = {ah[0] + a.x, ah[1] + a.y, ah[2] + a.z, ah[3] + a.w};
#pragma unroll
          for (int h = 0; h < 4; ++h) {
            float pp = p[h] >= 0.f ? p[h] : 0.2f * p[h];
            al[h] = expf(pp) * inv[h];
          }
          ((float4*)alpha_out)[es.x] = make_float4(al[0], al[1], al[2], al[3]);
        }
        int cl = min(64, deg - c0);
#pragma unroll 2
        for (int q = 0; q < cl; ++q) {
          int sq = __builtin_amdgcn_readlane(sreg, q);
          float a0 = readlane_f(al[0], q);
          float a1 = readlane_f(al[1], q);
          float a2 = readlane_f(al[2], q);
          float a3 = readlane_f(al[3], q);
          uint_t xw = ((const uint_t*)nfb)[(size_t)sq * 64 + lane];
          float xx = __uint_as_float(xw << 16);
          float xy = __uint_as_float(xw & 0xFFFF0000u);
          acc[0].x += a0 * xx; acc[0].y += a0 * xy;
          acc[1].x += a1 * xx; acc[1].y += a1 * xy;
          acc[2].x += a2 * xx; acc[2].y += a2 * xy;
          acc[3].x += a3 * xx; acc[3].y += a3 * xy;
        }
      }
    }
  }
  // G rows to LDS, k = lane*8 + h*2 + b (matches Pt perm)
  uint4 gwA, gwB;
  gwA.x = pack_bf2(accA[0].x, accA[0].y);
  gwA.y = pack_bf2(accA[1].x, accA[1].y);
  gwA.z = pack_bf2(accA[2].x, accA[2].y);
  gwA.w = pack_bf2(accA[3].x, accA[3].y);
  gwB.x = pack_bf2(accB[0].x, accB[0].y);
  gwB.y = pack_bf2(accB[1].x, accB[1].y);
  gwB.z = pack_bf2(accB[2].x, accB[2].y);
  gwB.w = pack_bf2(accB[3].x, accB[3].y);
  *(uint4*)&Gl[rowA * RS + lane * 8] = gwA;
  *(uint4*)&Gl[rowB * RS + lane * 8] = gwB;
  __syncthreads();

  // GEMM phase: wave w owns column tile nt = w (16 cols)
  int lr = lane & 15, lg = lane >> 4;
  f32x4 c0 = (f32x4){0.f, 0.f, 0.f, 0.f};
  const ushort_t* Pa = Pt + (size_t)lr * 512 + lg * 8 + (size_t)w * 16 * 512;
#pragma unroll
  for (int kt = 0; kt < 16; ++kt) {
    bf16x8 a = *(const bf16x8*)&Gl[lr * RS + kt * 32 + lg * 8];
    bf16x8 b0 = *(const bf16x8*)(Pa + kt * 32);
    c0 = __builtin_amdgcn_mfma_f32_16x16x32_bf16(a, b0, c0, 0, 0, 0);
  }
  int col0 = w * 16 + lr;
  float bb0 = b[col0];
#pragma unroll
  for (int r = 0; r < 4; ++r) {
    int row = j0 + lg * 4 + r;
    out[(size_t)row * 128 + col0] = c0[r] + bb0;
  }
}

extern "C" void kernel_launch(void* const* d_in, const int* in_sizes, int n_in,
                              void* d_out, int out_size, void* d_ws, size_t ws_size,
                              hipStream_t stream) {
  const float* nf      = (const float*)d_in[0];
  const float* Wsrc    = (const float*)d_in[1];
  const float* Wdst    = (const float*)d_in[2];
  const float* att_src = (const float*)d_in[3];
  const float* att_dst = (const float*)d_in[4];
  const float* Whigh   = (const float*)d_in[5];
  const float* bhigh   = (const float*)d_in[6];
  const int*   src     = (const int*)d_in[7];
  const int*   dst     = (const int*)d_in[8];

  char* ws = (char*)d_ws;
  float*    v_src  = (float*)(ws + OFF_VSRC);
  float*    v_dst  = (float*)(ws + OFF_VDST);
  ushort_t* Pt     = (ushort_t*)(ws + OFF_P);
  float4*   a_pack = (float4*)(ws + OFF_APK);
  int*      cnt    = (int*)(ws + OFF_CNT);
  int*      offs   = (int*)(ws + OFF_OFFS);
  int2*     sorted = (int2*)(ws + OFF_SORT);
  ushort_t* nfb    = (ushort_t*)(ws + OFF_NFB);
  float4*   ahsum  = (float4*)(ws + OFF_AHS);

  float* out_h     = (float*)d_out;                   // [20000,128]
  float* out_alpha = (float*)d_out + (size_t)N_HIGH * D;  // [200000,4]

  k_vp<<<768, 256, 0, stream>>>(Wsrc, Wdst, att_src, att_dst, Whigh,
                                v_src, v_dst, cnt, ahsum, Pt);
  k_nodehist<<<NP_BLOCKS + H_BLOCKS, 256, 0, stream>>>(
      nf, v_src, v_dst, a_pack, dst, cnt, nfb);
  k_scan<<<1, 1024, 0, stream>>>(cnt, offs);
  k_scatter<<<(N_EDGES + 255) / 256, 256, 0, stream>>>(
      dst, src, offs, cnt, sorted, a_pack, (float*)ahsum);
  k_mg<<<N_HIGH / 16, 512, 0, stream>>>(nfb, a_pack, ahsum, offs, sorted,
                                        Pt, bhigh, out_alpha, out_h);
}

// Round 17
// 108.753 us; speedup vs baseline: 1.3220x; 1.3220x over previous
//
#include <hip/hip_runtime.h>
#include <math.h>

#define N_NODES 100000
#define N_HIGH  20000
#define N_EDGES 200000
#define D       128
#define HEADS   4
#define EPSF    1e-16f

typedef __attribute__((ext_vector_type(8))) short bf16x8;
typedef __attribute__((ext_vector_type(4))) float f32x4;
typedef unsigned short ushort_t;
typedef unsigned int uint_t;

__device__ __forceinline__ ushort_t bf16_rn(float f) {
  uint_t u = __float_as_uint(f);
  u = u + 0x7FFFu + ((u >> 16) & 1u);   // round-to-nearest-even
  return (ushort_t)(u >> 16);
}
__device__ __forceinline__ uint_t pack_bf2(float x, float y) {
  return (uint_t)bf16_rn(x) | ((uint_t)bf16_rn(y) << 16);
}
__device__ __forceinline__ float readlane_f(float v, int q) {
  return __uint_as_float(__builtin_amdgcn_readlane(__float_as_uint(v), q));
}

// ---------------- workspace layout (bytes) ----------------
constexpr size_t OFF_VSRC = 0;                       // 512 f
constexpr size_t OFF_VDST = OFF_VSRC + 512 * 4;      // 512 f
constexpr size_t OFF_P    = OFF_VDST + 512 * 4;      // Pt bf16 [128][512] (region 256 KB)
constexpr size_t OFF_APK  = OFF_P    + 65536 * 4;    // a_pack float4[200000] = 3.2 MB
constexpr size_t OFF_CNT  = OFF_APK  + 800000 * 4;   // 20000 i
constexpr size_t OFF_OFFS = OFF_CNT  + 20000 * 4;    // 20001 i (padded)
constexpr size_t OFF_FILL = OFF_OFFS + 20004 * 4;    // (unused)
constexpr size_t OFF_SORT = OFF_FILL + 20000 * 4;    // 200000 int2 = 1.6 MB
constexpr size_t OFF_G    = OFF_SORT + 200000 * 8;   // (unused)
constexpr size_t OFF_NFB  = OFF_G    + 20000 * 512 * 2;  // nf bf16 [100000][128] = 25.6 MB
constexpr size_t OFF_AHS  = OFF_NFB  + (size_t)100000 * 128 * 2; // ahsum float4[20000] = 320 KB

// -------- fused: vecs (+zero cnt) | P  --------
__global__ __launch_bounds__(256) void k_vp(
    const float* __restrict__ Wsrc, const float* __restrict__ Wdst,
    const float* __restrict__ att_src, const float* __restrict__ att_dst,
    const float* __restrict__ Whigh,
    float* __restrict__ v_src, float* __restrict__ v_dst,
    int* __restrict__ cnt, ushort_t* __restrict__ Pt) {
  __shared__ float red[128];
  if (blockIdx.x < 256) {
    int gid = blockIdx.x * 256 + threadIdx.x;
    if (gid < N_HIGH) cnt[gid] = 0;

    int W = blockIdx.x * 4 + (threadIdx.x >> 6);   // 0..1023
    int lane = threadIdx.x & 63;
    int which = W >> 9;
    int idx = W & 511;
    int k = idx >> 2, h = idx & 3;
    const float* wrow = (which ? Wdst : Wsrc) + k * (HEADS * D) + h * D;
    const float* arow = (which ? att_src : att_dst) + h * D;
    float2 wv = ((const float2*)wrow)[lane];
    float2 av = ((const float2*)arow)[lane];
    float s = wv.x * av.x + wv.y * av.y;
#pragma unroll
    for (int o = 32; o; o >>= 1) s += __shfl_xor(s, o);
    if (lane == 0) {
      if (which) v_src[k * HEADS + h] = s;
      else       v_dst[k * HEADS + h] = s;
    }
  } else {
    int hk = blockIdx.x - 256;      // 0..511: (h,col)
    int h = hk >> 7, col = hk & 127;
    int d = threadIdx.x & 127, half = threadIdx.x >> 7;
    const float* ws = Wsrc + col * (HEADS * D) + h * D + half * 64;
    const float* wh = Whigh + (size_t)(half * 64) * D + d;
    float s = 0.f;
#pragma unroll 8
    for (int m = 0; m < 64; ++m) s += ws[m] * wh[(size_t)m * D];
    if (half) red[d] = s;
    __syncthreads();
    if (!half) {
      int kp = (col >> 1) * 8 + h * 2 + (col & 1);
      Pt[(size_t)d * 512 + kp] = bf16_rn(0.25f * (s + red[d]));
    }
  }
}

// -------- fused: nodeproj (+ nf->bf16 copy) | hist --------
// a_pack[2n] = a_srcn(n), a_pack[2n+1] = a_dstn(n)
#define NP_BLOCKS 1563            // ceil(100000/64)
#define H_BLOCKS  782             // ceil(200000/256)
__global__ __launch_bounds__(256) void k_nodehist(
    const float* __restrict__ nf,
    const float* __restrict__ v_src, const float* __restrict__ v_dst,
    float4* __restrict__ a_pack,
    const int* __restrict__ dst, int* __restrict__ cnt,
    ushort_t* __restrict__ nfb) {
  __shared__ float nfT[128 * 65];
  __shared__ float4 vsf4[128];
  __shared__ float4 vdf4[128];
  __shared__ float part[8][4][64];
  int t = threadIdx.x;
  if (blockIdx.x >= NP_BLOCKS) {
    int e = (blockIdx.x - NP_BLOCKS) * 256 + t;
    if (e < N_EDGES) atomicAdd(&cnt[dst[e]], 1);
    return;
  }
  int n0 = blockIdx.x * 64;

  if (t < 128) vsf4[t] = ((const float4*)v_src)[t];
  else vdf4[t - 128] = ((const float4*)v_dst)[t - 128];

  const float4* nf4 = (const float4*)nf;
#pragma unroll
  for (int j = 0; j < 8; ++j) {
    int f4 = j * 256 + t;
    int r = f4 >> 5, c4 = f4 & 31;
    int n = n0 + r;
    if (n > N_NODES - 1) n = N_NODES - 1;   // clamped dup rows write same bytes
    float4 g = nf4[(size_t)n * 32 + c4];
    nfT[(c4 * 4 + 0) * 65 + r] = g.x;
    nfT[(c4 * 4 + 1) * 65 + r] = g.y;
    nfT[(c4 * 4 + 2) * 65 + r] = g.z;
    nfT[(c4 * 4 + 3) * 65 + r] = g.w;
    ushort4 hb;
    hb.x = bf16_rn(g.x); hb.y = bf16_rn(g.y);
    hb.z = bf16_rn(g.z); hb.w = bf16_rn(g.w);
    ((ushort4*)nfb)[(size_t)n * 32 + c4] = hb;
  }
  __syncthreads();

  int l = t & 63, w = t >> 6;
  float as[4] = {0.f, 0.f, 0.f, 0.f};
  float ad[4] = {0.f, 0.f, 0.f, 0.f};
#pragma unroll 8
  for (int kk = 0; kk < 32; ++kk) {
    int k = w * 32 + kk;
    float x = nfT[k * 65 + l];
    float4 s4 = vsf4[k];
    float4 d4 = vdf4[k];
    as[0] += x * s4.x; as[1] += x * s4.y; as[2] += x * s4.z; as[3] += x * s4.w;
    ad[0] += x * d4.x; ad[1] += x * d4.y; ad[2] += x * d4.z; ad[3] += x * d4.w;
  }
#pragma unroll
  for (int v = 0; v < 4; ++v) {
    part[v][w][l] = as[v];
    part[v + 4][w][l] = ad[v];
  }
  __syncthreads();

  if (t < 64) {
    int ll = t;
    if (n0 + ll < N_NODES) {
      float4 o;
      o.x = part[0][0][ll] + part[0][1][ll] + part[0][2][ll] + part[0][3][ll];
      o.y = part[1][0][ll] + part[1][1][ll] + part[1][2][ll] + part[1][3][ll];
      o.z = part[2][0][ll] + part[2][1][ll] + part[2][2][ll] + part[2][3][ll];
      o.w = part[3][0][ll] + part[3][1][ll] + part[3][2][ll] + part[3][3][ll];
      a_pack[(size_t)(n0 + ll) * 2] = o;
    }
  } else if (t < 128) {
    int ll = t - 64;
    if (n0 + ll < N_NODES) {
      float4 o;
      o.x = part[4][0][ll] + part[4][1][ll] + part[4][2][ll] + part[4][3][ll];
      o.y = part[5][0][ll] + part[5][1][ll] + part[5][2][ll] + part[5][3][ll];
      o.z = part[6][0][ll] + part[6][1][ll] + part[6][2][ll] + part[6][3][ll];
      o.w = part[7][0][ll] + part[7][1][ll] + part[7][2][ll] + part[7][3][ll];
      a_pack[(size_t)(n0 + ll) * 2 + 1] = o;
    }
  }
}

// exclusive scan of cnt[20000] -> offs[20001]; shfl-based, ONE barrier
#define SCAN_PER 20
__global__ __launch_bounds__(1024) void k_scan(
    const int* __restrict__ cnt, int* __restrict__ offs) {
  __shared__ int wsum[16];
  int t = threadIdx.x;
  int lane = t & 63, wv = t >> 6;
  int base = t * SCAN_PER;
  int loc[SCAN_PER];
  int s = 0;
#pragma unroll
  for (int i = 0; i < SCAN_PER; ++i) {
    int idx = base + i;
    loc[i] = (idx < N_HIGH) ? cnt[idx] : 0;
    s += loc[i];
  }
  int tot = s;
#pragma unroll
  for (int o = 1; o < 64; o <<= 1) {
    int v = __shfl_up(tot, o);
    if (lane >= o) tot += v;
  }
  if (lane == 63) wsum[wv] = tot;
  __syncthreads();
  int wpre = 0;
  for (int i = 0; i < 16; ++i) wpre += (i < wv) ? wsum[i] : 0;
  int run = wpre + tot - s;
#pragma unroll
  for (int i = 0; i < SCAN_PER; ++i) {
    int idx = base + i;
    if (idx < N_HIGH) {
      offs[idx] = run;
      run += loc[i];
    }
  }
  if (t == 1023) offs[N_HIGH] = wpre + tot;
}

// counting-sort scatter: slot via atomicSub on cnt (no fill array)
__global__ void k_scatter(const int* __restrict__ dst, const int* __restrict__ src,
                          const int* __restrict__ offs,
                          int* __restrict__ cnt, int2* __restrict__ sorted) {
  int e = blockIdx.x * blockDim.x + threadIdx.x;
  if (e < N_EDGES) {
    int d = dst[e];
    int pos = offs[d] + (atomicSub(&cnt[d], 1) - 1);
    sorted[pos] = make_int2(e, src[e]);
  }
}

// per-hyperedge a_srcn segment sum: one wave per hyperedge, shuffle reduce.
__global__ __launch_bounds__(512) void k_ah(
    const float4* __restrict__ a_pack,
    const int* __restrict__ offs, const int2* __restrict__ sorted,
    float4* __restrict__ ahsum) {
  int j = blockIdx.x * 8 + (threadIdx.x >> 6);
  int lane = threadIdx.x & 63;
  int o0 = offs[j], o1 = offs[j + 1];
  float s[4] = {0.f, 0.f, 0.f, 0.f};
  for (int i = o0 + lane; i < o1; i += 64) {
    int2 es = sorted[i];
    float4 a = a_pack[(size_t)es.y * 2];
    s[0] += a.x; s[1] += a.y; s[2] += a.z; s[3] += a.w;
  }
#pragma unroll
  for (int o = 32; o; o >>= 1)
#pragma unroll
    for (int h = 0; h < 4; ++h) s[h] += __shfl_xor(s[h], o);
  if (lane == 0) ahsum[j] = make_float4(s[0], s[1], s[2], s[3]);
}

// -------- fused main+gemm: 512 thr = 8 waves; 16 hyperedges (2/wave) --------
// ah precomputed (k_ah) -> no a_srcn gather, no first shuffle chain in the
// serial path. Branch-free unrolled gather loop.
#define RS 520   // padded LDS row stride (ushorts): 2-way-free ds_read_b128
__global__ __launch_bounds__(512) void k_mg(
    const ushort_t* __restrict__ nfb,
    const float4* __restrict__ a_pack,
    const float4* __restrict__ ahsum,
    const int* __restrict__ offs, const int2* __restrict__ sorted,
    const ushort_t* __restrict__ Pt, const float* __restrict__ b,
    float* __restrict__ alpha_out, float* __restrict__ out) {
  __shared__ ushort_t Gl[16 * RS];          // 16.3 KB
  int t = threadIdx.x;
  int w = t >> 6, lane = t & 63;
  int j0 = blockIdx.x * 16;
  int rowA = w * 2, rowB = rowA + 1;
  int jA = j0 + rowA;
  int oA0 = offs[jA], oA1 = offs[jA + 1], oB1 = offs[jA + 2];
  int oB0 = oA1;
  int degA = oA1 - oA0, degB = oB1 - oB0;

  float2 accA[4], accB[4];
#pragma unroll
  for (int h = 0; h < 4; ++h) {
    accA[h] = make_float2(0.f, 0.f);
    accB[h] = make_float2(0.f, 0.f);
  }

  if (degA <= 64 && degB <= 64) {
    // ---- interleaved fast path (handles deg==0 via act masks) ----
    bool actA = lane < degA, actB = lane < degB;
    int idxA = min(oA0 + (actA ? lane : 0), N_EDGES - 1);
    int idxB = min(oB0 + (actB ? lane : 0), N_EDGES - 1);
    int2 esA = sorted[idxA];
    int2 esB = sorted[idxB];
    int eA = esA.x, srA = esA.y;
    int eB = esB.x, srB = esB.y;
    float4 z4 = make_float4(0.f, 0.f, 0.f, 0.f);
    float4 adA = z4, adB = z4;
    if (actA) adA = a_pack[(size_t)srA * 2 + 1];
    if (actB) adB = a_pack[(size_t)srB * 2 + 1];
    float4 ahA4 = ahsum[jA];
    float4 ahB4 = ahsum[jA + 1];
    float invA = 1.0f / (float)max(degA, 1);
    float invB = 1.0f / (float)max(degB, 1);

    float exA[4], exB[4];
    {
      float pA0 = ahA4.x * invA + adA.x, pA1 = ahA4.y * invA + adA.y;
      float pA2 = ahA4.z * invA + adA.z, pA3 = ahA4.w * invA + adA.w;
      float pB0 = ahB4.x * invB + adB.x, pB1 = ahB4.y * invB + adB.y;
      float pB2 = ahB4.z * invB + adB.z, pB3 = ahB4.w * invB + adB.w;
      pA0 = pA0 >= 0.f ? pA0 : 0.2f * pA0;
      pA1 = pA1 >= 0.f ? pA1 : 0.2f * pA1;
      pA2 = pA2 >= 0.f ? pA2 : 0.2f * pA2;
      pA3 = pA3 >= 0.f ? pA3 : 0.2f * pA3;
      pB0 = pB0 >= 0.f ? pB0 : 0.2f * pB0;
      pB1 = pB1 >= 0.f ? pB1 : 0.2f * pB1;
      pB2 = pB2 >= 0.f ? pB2 : 0.2f * pB2;
      pB3 = pB3 >= 0.f ? pB3 : 0.2f * pB3;
      exA[0] = actA ? expf(pA0) : 0.f;
      exA[1] = actA ? expf(pA1) : 0.f;
      exA[2] = actA ? expf(pA2) : 0.f;
      exA[3] = actA ? expf(pA3) : 0.f;
      exB[0] = actB ? expf(pB0) : 0.f;
      exB[1] = actB ? expf(pB1) : 0.f;
      exB[2] = actB ? expf(pB2) : 0.f;
      exB[3] = actB ? expf(pB3) : 0.f;
    }
    float seA[4] = {exA[0], exA[1], exA[2], exA[3]};
    float seB[4] = {exB[0], exB[1], exB[2], exB[3]};
#pragma unroll
    for (int o = 32; o; o >>= 1)
#pragma unroll
      for (int h = 0; h < 4; ++h) {
        seA[h] += __shfl_xor(seA[h], o);
        seB[h] += __shfl_xor(seB[h], o);
      }
    float alA[4], alB[4];
#pragma unroll
    for (int h = 0; h < 4; ++h) {
      alA[h] = exA[h] / (seA[h] + EPSF);
      alB[h] = exB[h] / (seB[h] + EPSF);
    }
    if (actA)
      ((float4*)alpha_out)[eA] = make_float4(alA[0], alA[1], alA[2], alA[3]);
    if (actB)
      ((float4*)alpha_out)[eB] = make_float4(alB[0], alB[1], alB[2], alB[3]);

    // branch-free fused gather loop: both hyperedges every iteration
    const uint_t* __restrict__ nfbu = (const uint_t*)nfb;
    int dmax = max(degA, degB);
#pragma unroll 8
    for (int q = 0; q < dmax; ++q) {
      int sqA = __builtin_amdgcn_readlane(srA, q);
      int sqB = __builtin_amdgcn_readlane(srB, q);
      uint_t xwA = nfbu[(size_t)sqA * 64 + lane];
      uint_t xwB = nfbu[(size_t)sqB * 64 + lane];
      float a0 = readlane_f(alA[0], q);
      float a1 = readlane_f(alA[1], q);
      float a2 = readlane_f(alA[2], q);
      float a3 = readlane_f(alA[3], q);
      float b0 = readlane_f(alB[0], q);
      float b1 = readlane_f(alB[1], q);
      float b2 = readlane_f(alB[2], q);
      float b3 = readlane_f(alB[3], q);
      float xAx = __uint_as_float(xwA << 16);
      float xAy = __uint_as_float(xwA & 0xFFFF0000u);
      float xBx = __uint_as_float(xwB << 16);
      float xBy = __uint_as_float(xwB & 0xFFFF0000u);
      accA[0].x += a0 * xAx; accA[0].y += a0 * xAy;
      accA[1].x += a1 * xAx; accA[1].y += a1 * xAy;
      accA[2].x += a2 * xAx; accA[2].y += a2 * xAy;
      accA[3].x += a3 * xAx; accA[3].y += a3 * xAy;
      accB[0].x += b0 * xBx; accB[0].y += b0 * xBy;
      accB[1].x += b1 * xBx; accB[1].y += b1 * xBy;
      accB[2].x += b2 * xBx; accB[2].y += b2 * xBy;
      accB[3].x += b3 * xBx; accB[3].y += b3 * xBy;
    }
  } else {
    // ---- rare fallback: general chunked path, works for any deg ----
    for (int pick = 0; pick < 2; ++pick) {
      int o0 = pick ? oB0 : oA0;
      int deg = pick ? degB : degA;
      int jj = jA + pick;
      float2* acc = pick ? accB : accA;

      float4 ah4 = ahsum[jj];
      float invdeg = 1.0f / (float)max(deg, 1);
      float ah[4] = {ah4.x * invdeg, ah4.y * invdeg, ah4.z * invdeg, ah4.w * invdeg};

      float se[4] = {0.f, 0.f, 0.f, 0.f};
      for (int i = lane; i < deg; i += 64) {
        int2 es = sorted[o0 + i];
        float4 a = a_pack[(size_t)es.y * 2 + 1];
        float p[4] = {ah[0] + a.x, ah[1] + a.y, ah[2] + a.z, ah[3] + a.w};
#pragma unroll
        for (int h = 0; h < 4; ++h) {
          float pp = p[h] >= 0.f ? p[h] : 0.2f * p[h];
          se[h] += expf(pp);
        }
      }
#pragma unroll
      for (int o = 32; o; o >>= 1)
#pragma unroll
        for (int h = 0; h < 4; ++h) se[h] += __shfl_xor(se[h], o);
      float inv[4];
#pragma unroll
      for (int h = 0; h < 4; ++h) inv[h] = 1.0f / (se[h] + EPSF);

      for (int c0 = 0; c0 < deg; c0 += 64) {
        int i = c0 + lane;
        float al[4] = {0.f, 0.f, 0.f, 0.f};
        int sreg = 0;
        if (i < deg) {
          int2 es = sorted[o0 + i];
          sreg = es.y;
          float4 a = a_pack[(size_t)sreg * 2 + 1];
          float p[4] = {ah[0] + a.x, ah[1] + a.y, ah[2] + a.z, ah[3] + a.w};
#pragma unroll
          for (int h = 0; h < 4; ++h) {
            float pp = p[h] >= 0.f ? p[h] : 0.2f * p[h];
            al[h] = expf(pp) * inv[h];
          }
          ((float4*)alpha_out)[es.x] = make_float4(al[0], al[1], al[2], al[3]);
        }
        int cl = min(64, deg - c0);
#pragma unroll 2
        for (int q = 0; q < cl; ++q) {
          int sq = __builtin_amdgcn_readlane(sreg, q);
          float a0 = readlane_f(al[0], q);
          float a1 = readlane_f(al[1], q);
          float a2 = readlane_f(al[2], q);
          float a3 = readlane_f(al[3], q);
          uint_t xw = ((const uint_t*)nfb)[(size_t)sq * 64 + lane];
          float xx = __uint_as_float(xw << 16);
          float xy = __uint_as_float(xw & 0xFFFF0000u);
          acc[0].x += a0 * xx; acc[0].y += a0 * xy;
          acc[1].x += a1 * xx; acc[1].y += a1 * xy;
          acc[2].x += a2 * xx; acc[2].y += a2 * xy;
          acc[3].x += a3 * xx; acc[3].y += a3 * xy;
        }
      }
    }
  }
  // G rows to LDS, k = lane*8 + h*2 + b (matches Pt perm)
  uint4 gwA, gwB;
  gwA.x = pack_bf2(accA[0].x, accA[0].y);
  gwA.y = pack_bf2(accA[1].x, accA[1].y);
  gwA.z = pack_bf2(accA[2].x, accA[2].y);
  gwA.w = pack_bf2(accA[3].x, accA[3].y);
  gwB.x = pack_bf2(accB[0].x, accB[0].y);
  gwB.y = pack_bf2(accB[1].x, accB[1].y);
  gwB.z = pack_bf2(accB[2].x, accB[2].y);
  gwB.w = pack_bf2(accB[3].x, accB[3].y);
  *(uint4*)&Gl[rowA * RS + lane * 8] = gwA;
  *(uint4*)&Gl[rowB * RS + lane * 8] = gwB;
  __syncthreads();

  // GEMM phase: wave w owns column tile nt = w (16 cols)
  int lr = lane & 15, lg = lane >> 4;
  f32x4 c0 = (f32x4){0.f, 0.f, 0.f, 0.f};
  const ushort_t* Pa = Pt + (size_t)lr * 512 + lg * 8 + (size_t)w * 16 * 512;
#pragma unroll
  for (int kt = 0; kt < 16; ++kt) {
    bf16x8 a = *(const bf16x8*)&Gl[lr * RS + kt * 32 + lg * 8];
    bf16x8 b0 = *(const bf16x8*)(Pa + kt * 32);
    c0 = __builtin_amdgcn_mfma_f32_16x16x32_bf16(a, b0, c0, 0, 0, 0);
  }
  int col0 = w * 16 + lr;
  float bb0 = b[col0];
#pragma unroll
  for (int r = 0; r < 4; ++r) {
    int row = j0 + lg * 4 + r;
    out[(size_t)row * 128 + col0] = c0[r] + bb0;
  }
}

extern "C" void kernel_launch(void* const* d_in, const int* in_sizes, int n_in,
                              void* d_out, int out_size, void* d_ws, size_t ws_size,
                              hipStream_t stream) {
  const float* nf      = (const float*)d_in[0];
  const float* Wsrc    = (const float*)d_in[1];
  const float* Wdst    = (const float*)d_in[2];
  const float* att_src = (const float*)d_in[3];
  const float* att_dst = (const float*)d_in[4];
  const float* Whigh   = (const float*)d_in[5];
  const float* bhigh   = (const float*)d_in[6];
  const int*   src     = (const int*)d_in[7];
  const int*   dst     = (const int*)d_in[8];

  char* ws = (char*)d_ws;
  float*    v_src  = (float*)(ws + OFF_VSRC);
  float*    v_dst  = (float*)(ws + OFF_VDST);
  ushort_t* Pt     = (ushort_t*)(ws + OFF_P);
  float4*   a_pack = (float4*)(ws + OFF_APK);
  int*      cnt    = (int*)(ws + OFF_CNT);
  int*      offs   = (int*)(ws + OFF_OFFS);
  int2*     sorted = (int2*)(ws + OFF_SORT);
  ushort_t* nfb    = (ushort_t*)(ws + OFF_NFB);
  float4*   ahsum  = (float4*)(ws + OFF_AHS);

  float* out_h     = (float*)d_out;                   // [20000,128]
  float* out_alpha = (float*)d_out + (size_t)N_HIGH * D;  // [200000,4]

  k_vp<<<768, 256, 0, stream>>>(Wsrc, Wdst, att_src, att_dst, Whigh,
                                v_src, v_dst, cnt, Pt);
  k_nodehist<<<NP_BLOCKS + H_BLOCKS, 256, 0, stream>>>(
      nf, v_src, v_dst, a_pack, dst, cnt, nfb);
  k_scan<<<1, 1024, 0, stream>>>(cnt, offs);
  k_scatter<<<(N_EDGES + 255) / 256, 256, 0, stream>>>(
      dst, src, offs, cnt, sorted);
  k_ah<<<N_HIGH / 8, 512, 0, stream>>>(a_pack, offs, sorted, ahsum);
  k_mg<<<N_HIGH / 16, 512, 0, stream>>>(nfb, a_pack, ahsum, offs, sorted,
                                        Pt, bhigh, out_alpha, out_h);
}

// Round 18
// 105.095 us; speedup vs baseline: 1.3680x; 1.0348x over previous
//
#include <hip/hip_runtime.h>
#include <math.h>

#define N_NODES 100000
#define N_HIGH  20000
#define N_EDGES 200000
#define D       128
#define HEADS   4
#define EPSF    1e-16f

typedef __attribute__((ext_vector_type(8))) short bf16x8;
typedef __attribute__((ext_vector_type(4))) float f32x4;
typedef unsigned short ushort_t;
typedef unsigned int uint_t;

__device__ __forceinline__ ushort_t bf16_rn(float f) {
  uint_t u = __float_as_uint(f);
  u = u + 0x7FFFu + ((u >> 16) & 1u);   // round-to-nearest-even
  return (ushort_t)(u >> 16);
}
__device__ __forceinline__ uint_t pack_bf2(float x, float y) {
  return (uint_t)bf16_rn(x) | ((uint_t)bf16_rn(y) << 16);
}
__device__ __forceinline__ float readlane_f(float v, int q) {
  return __uint_as_float(__builtin_amdgcn_readlane(__float_as_uint(v), q));
}

// ---------------- workspace layout (bytes) ----------------
constexpr size_t OFF_VSRC = 0;                       // 512 f
constexpr size_t OFF_VDST = OFF_VSRC + 512 * 4;      // 512 f
constexpr size_t OFF_P    = OFF_VDST + 512 * 4;      // Pt bf16 [128][512] (region 256 KB)
constexpr size_t OFF_APK  = OFF_P    + 65536 * 4;    // a_pack float4[200000] = 3.2 MB
constexpr size_t OFF_CNT  = OFF_APK  + 800000 * 4;   // 20000 i
constexpr size_t OFF_OFFS = OFF_CNT  + 20000 * 4;    // 20001 i (padded)
constexpr size_t OFF_FILL = OFF_OFFS + 20004 * 4;    // (unused)
constexpr size_t OFF_SORT = OFF_FILL + 20000 * 4;    // 200000 int2 = 1.6 MB
constexpr size_t OFF_G    = OFF_SORT + 200000 * 8;   // (unused)
constexpr size_t OFF_NFB  = OFF_G    + 20000 * 512 * 2;  // nf bf16 [100000][128] = 25.6 MB
constexpr size_t OFF_AHS  = OFF_NFB  + (size_t)100000 * 128 * 2; // ahsum float4[20000] = 320 KB

// -------- fused: vecs (+zero cnt) | P  --------
__global__ __launch_bounds__(256) void k_vp(
    const float* __restrict__ Wsrc, const float* __restrict__ Wdst,
    const float* __restrict__ att_src, const float* __restrict__ att_dst,
    const float* __restrict__ Whigh,
    float* __restrict__ v_src, float* __restrict__ v_dst,
    int* __restrict__ cnt, ushort_t* __restrict__ Pt) {
  __shared__ float red[128];
  if (blockIdx.x < 256) {
    int gid = blockIdx.x * 256 + threadIdx.x;
    if (gid < N_HIGH) cnt[gid] = 0;

    int W = blockIdx.x * 4 + (threadIdx.x >> 6);   // 0..1023
    int lane = threadIdx.x & 63;
    int which = W >> 9;
    int idx = W & 511;
    int k = idx >> 2, h = idx & 3;
    const float* wrow = (which ? Wdst : Wsrc) + k * (HEADS * D) + h * D;
    const float* arow = (which ? att_src : att_dst) + h * D;
    float2 wv = ((const float2*)wrow)[lane];
    float2 av = ((const float2*)arow)[lane];
    float s = wv.x * av.x + wv.y * av.y;
#pragma unroll
    for (int o = 32; o; o >>= 1) s += __shfl_xor(s, o);
    if (lane == 0) {
      if (which) v_src[k * HEADS + h] = s;
      else       v_dst[k * HEADS + h] = s;
    }
  } else {
    int hk = blockIdx.x - 256;      // 0..511: (h,col)
    int h = hk >> 7, col = hk & 127;
    int d = threadIdx.x & 127, half = threadIdx.x >> 7;
    const float* ws = Wsrc + col * (HEADS * D) + h * D + half * 64;
    const float* wh = Whigh + (size_t)(half * 64) * D + d;
    float s = 0.f;
#pragma unroll 8
    for (int m = 0; m < 64; ++m) s += ws[m] * wh[(size_t)m * D];
    if (half) red[d] = s;
    __syncthreads();
    if (!half) {
      int kp = (col >> 1) * 8 + h * 2 + (col & 1);
      Pt[(size_t)d * 512 + kp] = bf16_rn(0.25f * (s + red[d]));
    }
  }
}

// -------- fused: nodeproj (+ nf->bf16 copy) | hist --------
// a_pack[2n] = a_srcn(n), a_pack[2n+1] = a_dstn(n)
#define NP_BLOCKS 1563            // ceil(100000/64)
#define H_BLOCKS  782             // ceil(200000/256)
__global__ __launch_bounds__(256) void k_nodehist(
    const float* __restrict__ nf,
    const float* __restrict__ v_src, const float* __restrict__ v_dst,
    float4* __restrict__ a_pack,
    const int* __restrict__ dst, int* __restrict__ cnt,
    ushort_t* __restrict__ nfb) {
  __shared__ float nfT[128 * 65];
  __shared__ float4 vsf4[128];
  __shared__ float4 vdf4[128];
  __shared__ float part[8][4][64];
  int t = threadIdx.x;
  if (blockIdx.x >= NP_BLOCKS) {
    int e = (blockIdx.x - NP_BLOCKS) * 256 + t;
    if (e < N_EDGES) atomicAdd(&cnt[dst[e]], 1);
    return;
  }
  int n0 = blockIdx.x * 64;

  if (t < 128) vsf4[t] = ((const float4*)v_src)[t];
  else vdf4[t - 128] = ((const float4*)v_dst)[t - 128];

  const float4* nf4 = (const float4*)nf;
#pragma unroll
  for (int j = 0; j < 8; ++j) {
    int f4 = j * 256 + t;
    int r = f4 >> 5, c4 = f4 & 31;
    int n = n0 + r;
    if (n > N_NODES - 1) n = N_NODES - 1;   // clamped dup rows write same bytes
    float4 g = nf4[(size_t)n * 32 + c4];
    nfT[(c4 * 4 + 0) * 65 + r] = g.x;
    nfT[(c4 * 4 + 1) * 65 + r] = g.y;
    nfT[(c4 * 4 + 2) * 65 + r] = g.z;
    nfT[(c4 * 4 + 3) * 65 + r] = g.w;
    ushort4 hb;
    hb.x = bf16_rn(g.x); hb.y = bf16_rn(g.y);
    hb.z = bf16_rn(g.z); hb.w = bf16_rn(g.w);
    ((ushort4*)nfb)[(size_t)n * 32 + c4] = hb;
  }
  __syncthreads();

  int l = t & 63, w = t >> 6;
  float as[4] = {0.f, 0.f, 0.f, 0.f};
  float ad[4] = {0.f, 0.f, 0.f, 0.f};
#pragma unroll 8
  for (int kk = 0; kk < 32; ++kk) {
    int k = w * 32 + kk;
    float x = nfT[k * 65 + l];
    float4 s4 = vsf4[k];
    float4 d4 = vdf4[k];
    as[0] += x * s4.x; as[1] += x * s4.y; as[2] += x * s4.z; as[3] += x * s4.w;
    ad[0] += x * d4.x; ad[1] += x * d4.y; ad[2] += x * d4.z; ad[3] += x * d4.w;
  }
#pragma unroll
  for (int v = 0; v < 4; ++v) {
    part[v][w][l] = as[v];
    part[v + 4][w][l] = ad[v];
  }
  __syncthreads();

  if (t < 64) {
    int ll = t;
    if (n0 + ll < N_NODES) {
      float4 o;
      o.x = part[0][0][ll] + part[0][1][ll] + part[0][2][ll] + part[0][3][ll];
      o.y = part[1][0][ll] + part[1][1][ll] + part[1][2][ll] + part[1][3][ll];
      o.z = part[2][0][ll] + part[2][1][ll] + part[2][2][ll] + part[2][3][ll];
      o.w = part[3][0][ll] + part[3][1][ll] + part[3][2][ll] + part[3][3][ll];
      a_pack[(size_t)(n0 + ll) * 2] = o;
    }
  } else if (t < 128) {
    int ll = t - 64;
    if (n0 + ll < N_NODES) {
      float4 o;
      o.x = part[4][0][ll] + part[4][1][ll] + part[4][2][ll] + part[4][3][ll];
      o.y = part[5][0][ll] + part[5][1][ll] + part[5][2][ll] + part[5][3][ll];
      o.z = part[6][0][ll] + part[6][1][ll] + part[6][2][ll] + part[6][3][ll];
      o.w = part[7][0][ll] + part[7][1][ll] + part[7][2][ll] + part[7][3][ll];
      a_pack[(size_t)(n0 + ll) * 2 + 1] = o;
    }
  }
}

// exclusive scan of cnt[20000] -> offs[20001]; shfl-based, ONE barrier
#define SCAN_PER 20
__global__ __launch_bounds__(1024) void k_scan(
    const int* __restrict__ cnt, int* __restrict__ offs) {
  __shared__ int wsum[16];
  int t = threadIdx.x;
  int lane = t & 63, wv = t >> 6;
  int base = t * SCAN_PER;
  int loc[SCAN_PER];
  int s = 0;
#pragma unroll
  for (int i = 0; i < SCAN_PER; ++i) {
    int idx = base + i;
    loc[i] = (idx < N_HIGH) ? cnt[idx] : 0;
    s += loc[i];
  }
  int tot = s;
#pragma unroll
  for (int o = 1; o < 64; o <<= 1) {
    int v = __shfl_up(tot, o);
    if (lane >= o) tot += v;
  }
  if (lane == 63) wsum[wv] = tot;
  __syncthreads();
  int wpre = 0;
  for (int i = 0; i < 16; ++i) wpre += (i < wv) ? wsum[i] : 0;
  int run = wpre + tot - s;
#pragma unroll
  for (int i = 0; i < SCAN_PER; ++i) {
    int idx = base + i;
    if (idx < N_HIGH) {
      offs[idx] = run;
      run += loc[i];
    }
  }
  if (t == 1023) offs[N_HIGH] = wpre + tot;
}

// counting-sort scatter: slot via atomicSub on cnt (no fill array)
__global__ void k_scatter(const int* __restrict__ dst, const int* __restrict__ src,
                          const int* __restrict__ offs,
                          int* __restrict__ cnt, int2* __restrict__ sorted) {
  int e = blockIdx.x * blockDim.x + threadIdx.x;
  if (e < N_EDGES) {
    int d = dst[e];
    int pos = offs[d] + (atomicSub(&cnt[d], 1) - 1);
    sorted[pos] = make_int2(e, src[e]);
  }
}

// per-hyperedge a_srcn segment sum: one wave per hyperedge, shuffle reduce.
__global__ __launch_bounds__(512) void k_ah(
    const float4* __restrict__ a_pack,
    const int* __restrict__ offs, const int2* __restrict__ sorted,
    float4* __restrict__ ahsum) {
  int j = blockIdx.x * 8 + (threadIdx.x >> 6);
  int lane = threadIdx.x & 63;
  int o0 = offs[j], o1 = offs[j + 1];
  float s[4] = {0.f, 0.f, 0.f, 0.f};
  for (int i = o0 + lane; i < o1; i += 64) {
    int2 es = sorted[i];
    float4 a = a_pack[(size_t)es.y * 2];
    s[0] += a.x; s[1] += a.y; s[2] += a.z; s[3] += a.w;
  }
#pragma unroll
  for (int o = 32; o; o >>= 1)
#pragma unroll
    for (int h = 0; h < 4; ++h) s[h] += __shfl_xor(s[h], o);
  if (lane == 0) ahsum[j] = make_float4(s[0], s[1], s[2], s[3]);
}

// -------- fused main+gemm: 512 thr = 8 waves; 16 hyperedges (2/wave) --------
// Gather loop runs in chunks of 8: ALL 16 independent loads issued into
// registers first, then the FMAs -> staggered vmcnt instead of per-load
// serialization. Pad iterations (q>=deg) are exact no-ops: alpha==0 and the
// clamped sorted index makes pad rows == lane0's row (L1-hit).
#define RS 520   // padded LDS row stride (ushorts): 2-way-free ds_read_b128
__global__ __launch_bounds__(512) void k_mg(
    const ushort_t* __restrict__ nfb,
    const float4* __restrict__ a_pack,
    const float4* __restrict__ ahsum,
    const int* __restrict__ offs, const int2* __restrict__ sorted,
    const ushort_t* __restrict__ Pt, const float* __restrict__ b,
    float* __restrict__ alpha_out, float* __restrict__ out) {
  __shared__ ushort_t Gl[16 * RS];          // 16.3 KB
  int t = threadIdx.x;
  int w = t >> 6, lane = t & 63;
  int j0 = blockIdx.x * 16;
  int rowA = w * 2, rowB = rowA + 1;
  int jA = j0 + rowA;
  int oA0 = offs[jA], oA1 = offs[jA + 1], oB1 = offs[jA + 2];
  int oB0 = oA1;
  int degA = oA1 - oA0, degB = oB1 - oB0;

  float2 accA[4], accB[4];
#pragma unroll
  for (int h = 0; h < 4; ++h) {
    accA[h] = make_float2(0.f, 0.f);
    accB[h] = make_float2(0.f, 0.f);
  }

  if (degA <= 64 && degB <= 64) {
    // ---- interleaved fast path (handles deg==0 via act masks) ----
    bool actA = lane < degA, actB = lane < degB;
    int idxA = min(oA0 + (actA ? lane : 0), N_EDGES - 1);
    int idxB = min(oB0 + (actB ? lane : 0), N_EDGES - 1);
    int2 esA = sorted[idxA];
    int2 esB = sorted[idxB];
    int eA = esA.x, srA = esA.y;
    int eB = esB.x, srB = esB.y;
    float4 z4 = make_float4(0.f, 0.f, 0.f, 0.f);
    float4 adA = z4, adB = z4;
    if (actA) adA = a_pack[(size_t)srA * 2 + 1];
    if (actB) adB = a_pack[(size_t)srB * 2 + 1];
    float4 ahA4 = ahsum[jA];
    float4 ahB4 = ahsum[jA + 1];
    float invA = 1.0f / (float)max(degA, 1);
    float invB = 1.0f / (float)max(degB, 1);

    float exA[4], exB[4];
    {
      float pA0 = ahA4.x * invA + adA.x, pA1 = ahA4.y * invA + adA.y;
      float pA2 = ahA4.z * invA + adA.z, pA3 = ahA4.w * invA + adA.w;
      float pB0 = ahB4.x * invB + adB.x, pB1 = ahB4.y * invB + adB.y;
      float pB2 = ahB4.z * invB + adB.z, pB3 = ahB4.w * invB + adB.w;
      pA0 = pA0 >= 0.f ? pA0 : 0.2f * pA0;
      pA1 = pA1 >= 0.f ? pA1 : 0.2f * pA1;
      pA2 = pA2 >= 0.f ? pA2 : 0.2f * pA2;
      pA3 = pA3 >= 0.f ? pA3 : 0.2f * pA3;
      pB0 = pB0 >= 0.f ? pB0 : 0.2f * pB0;
      pB1 = pB1 >= 0.f ? pB1 : 0.2f * pB1;
      pB2 = pB2 >= 0.f ? pB2 : 0.2f * pB2;
      pB3 = pB3 >= 0.f ? pB3 : 0.2f * pB3;
      exA[0] = actA ? expf(pA0) : 0.f;
      exA[1] = actA ? expf(pA1) : 0.f;
      exA[2] = actA ? expf(pA2) : 0.f;
      exA[3] = actA ? expf(pA3) : 0.f;
      exB[0] = actB ? expf(pB0) : 0.f;
      exB[1] = actB ? expf(pB1) : 0.f;
      exB[2] = actB ? expf(pB2) : 0.f;
      exB[3] = actB ? expf(pB3) : 0.f;
    }
    float seA[4] = {exA[0], exA[1], exA[2], exA[3]};
    float seB[4] = {exB[0], exB[1], exB[2], exB[3]};
#pragma unroll
    for (int o = 32; o; o >>= 1)
#pragma unroll
      for (int h = 0; h < 4; ++h) {
        seA[h] += __shfl_xor(seA[h], o);
        seB[h] += __shfl_xor(seB[h], o);
      }
    float alA[4], alB[4];
#pragma unroll
    for (int h = 0; h < 4; ++h) {
      alA[h] = exA[h] / (seA[h] + EPSF);
      alB[h] = exB[h] / (seB[h] + EPSF);
    }
    if (actA)
      ((float4*)alpha_out)[eA] = make_float4(alA[0], alA[1], alA[2], alA[3]);
    if (actB)
      ((float4*)alpha_out)[eB] = make_float4(alB[0], alB[1], alB[2], alB[3]);

    // chunked batched gather: 16 loads issued, then 128 FMAs
    const uint_t* __restrict__ nfbu = (const uint_t*)nfb;
    int dmax8 = (max(degA, degB) + 7) & ~7;
    for (int c0 = 0; c0 < dmax8; c0 += 8) {
      uint_t xa[8], xb[8];
#pragma unroll
      for (int i = 0; i < 8; ++i) {
        int sqA = __builtin_amdgcn_readlane(srA, c0 + i);
        int sqB = __builtin_amdgcn_readlane(srB, c0 + i);
        xa[i] = nfbu[(size_t)sqA * 64 + lane];
        xb[i] = nfbu[(size_t)sqB * 64 + lane];
      }
#pragma unroll
      for (int i = 0; i < 8; ++i) {
        int q = c0 + i;
        float a0 = readlane_f(alA[0], q);
        float a1 = readlane_f(alA[1], q);
        float a2 = readlane_f(alA[2], q);
        float a3 = readlane_f(alA[3], q);
        float b0 = readlane_f(alB[0], q);
        float b1 = readlane_f(alB[1], q);
        float b2 = readlane_f(alB[2], q);
        float b3 = readlane_f(alB[3], q);
        float xAx = __uint_as_float(xa[i] << 16);
        float xAy = __uint_as_float(xa[i] & 0xFFFF0000u);
        float xBx = __uint_as_float(xb[i] << 16);
        float xBy = __uint_as_float(xb[i] & 0xFFFF0000u);
        accA[0].x += a0 * xAx; accA[0].y += a0 * xAy;
        accA[1].x += a1 * xAx; accA[1].y += a1 * xAy;
        accA[2].x += a2 * xAx; accA[2].y += a2 * xAy;
        accA[3].x += a3 * xAx; accA[3].y += a3 * xAy;
        accB[0].x += b0 * xBx; accB[0].y += b0 * xBy;
        accB[1].x += b1 * xBx; accB[1].y += b1 * xBy;
        accB[2].x += b2 * xBx; accB[2].y += b2 * xBy;
        accB[3].x += b3 * xBx; accB[3].y += b3 * xBy;
      }
    }
  } else {
    // ---- rare fallback: general chunked path, works for any deg ----
    for (int pick = 0; pick < 2; ++pick) {
      int o0 = pick ? oB0 : oA0;
      int deg = pick ? degB : degA;
      int jj = jA + pick;
      float2* acc = pick ? accB : accA;

      float4 ah4 = ahsum[jj];
      float invdeg = 1.0f / (float)max(deg, 1);
      float ah[4] = {ah4.x * invdeg, ah4.y * invdeg, ah4.z * invdeg, ah4.w * invdeg};

      float se[4] = {0.f, 0.f, 0.f, 0.f};
      for (int i = lane; i < deg; i += 64) {
        int2 es = sorted[o0 + i];
        float4 a = a_pack[(size_t)es.y * 2 + 1];
        float p[4] = {ah[0] + a.x, ah[1] + a.y, ah[2] + a.z, ah[3] + a.w};
#pragma unroll
        for (int h = 0; h < 4; ++h) {
          float pp = p[h] >= 0.f ? p[h] : 0.2f * p[h];
          se[h] += expf(pp);
        }
      }
#pragma unroll
      for (int o = 32; o; o >>= 1)
#pragma unroll
        for (int h = 0; h < 4; ++h) se[h] += __shfl_xor(se[h], o);
      float inv[4];
#pragma unroll
      for (int h = 0; h < 4; ++h) inv[h] = 1.0f / (se[h] + EPSF);

      for (int c0 = 0; c0 < deg; c0 += 64) {
        int i = c0 + lane;
        float al[4] = {0.f, 0.f, 0.f, 0.f};
        int sreg = 0;
        if (i < deg) {
          int2 es = sorted[o0 + i];
          sreg = es.y;
          float4 a = a_pack[(size_t)sreg * 2 + 1];
          float p[4] = {ah[0] + a.x, ah[1] + a.y, ah[2] + a.z, ah[3] + a.w};
#pragma unroll
          for (int h = 0; h < 4; ++h) {
            float pp = p[h] >= 0.f ? p[h] : 0.2f * p[h];
            al[h] = expf(pp) * inv[h];
          }
          ((float4*)alpha_out)[es.x] = make_float4(al[0], al[1], al[2], al[3]);
        }
        int cl = min(64, deg - c0);
#pragma unroll 2
        for (int q = 0; q < cl; ++q) {
          int sq = __builtin_amdgcn_readlane(sreg, q);
          float a0 = readlane_f(al[0], q);
          float a1 = readlane_f(al[1], q);
          float a2 = readlane_f(al[2], q);
          float a3 = readlane_f(al[3], q);
          uint_t xw = ((const uint_t*)nfb)[(size_t)sq * 64 + lane];
          float xx = __uint_as_float(xw << 16);
          float xy = __uint_as_float(xw & 0xFFFF0000u);
          acc[0].x += a0 * xx; acc[0].y += a0 * xy;
          acc[1].x += a1 * xx; acc[1].y += a1 * xy;
          acc[2].x += a2 * xx; acc[2].y += a2 * xy;
          acc[3].x += a3 * xx; acc[3].y += a3 * xy;
        }
      }
    }
  }
  // G rows to LDS, k = lane*8 + h*2 + b (matches Pt perm)
  uint4 gwA, gwB;
  gwA.x = pack_bf2(accA[0].x, accA[0].y);
  gwA.y = pack_bf2(accA[1].x, accA[1].y);
  gwA.z = pack_bf2(accA[2].x, accA[2].y);
  gwA.w = pack_bf2(accA[3].x, accA[3].y);
  gwB.x = pack_bf2(accB[0].x, accB[0].y);
  gwB.y = pack_bf2(accB[1].x, accB[1].y);
  gwB.z = pack_bf2(accB[2].x, accB[2].y);
  gwB.w = pack_bf2(accB[3].x, accB[3].y);
  *(uint4*)&Gl[rowA * RS + lane * 8] = gwA;
  *(uint4*)&Gl[rowB * RS + lane * 8] = gwB;
  __syncthreads();

  // GEMM phase: wave w owns column tile nt = w (16 cols)
  int lr = lane & 15, lg = lane >> 4;
  f32x4 c0 = (f32x4){0.f, 0.f, 0.f, 0.f};
  const ushort_t* Pa = Pt + (size_t)lr * 512 + lg * 8 + (size_t)w * 16 * 512;
#pragma unroll
  for (int kt = 0; kt < 16; ++kt) {
    bf16x8 a = *(const bf16x8*)&Gl[lr * RS + kt * 32 + lg * 8];
    bf16x8 b0 = *(const bf16x8*)(Pa + kt * 32);
    c0 = __builtin_amdgcn_mfma_f32_16x16x32_bf16(a, b0, c0, 0, 0, 0);
  }
  int col0 = w * 16 + lr;
  float bb0 = b[col0];
#pragma unroll
  for (int r = 0; r < 4; ++r) {
    int row = j0 + lg * 4 + r;
    out[(size_t)row * 128 + col0] = c0[r] + bb0;
  }
}

extern "C" void kernel_launch(void* const* d_in, const int* in_sizes, int n_in,
                              void* d_out, int out_size, void* d_ws, size_t ws_size,
                              hipStream_t stream) {
  const float* nf      = (const float*)d_in[0];
  const float* Wsrc    = (const float*)d_in[1];
  const float* Wdst    = (const float*)d_in[2];
  const float* att_src = (const float*)d_in[3];
  const float* att_dst = (const float*)d_in[4];
  const float* Whigh   = (const float*)d_in[5];
  const float* bhigh   = (const float*)d_in[6];
  const int*   src     = (const int*)d_in[7];
  const int*   dst     = (const int*)d_in[8];

  char* ws = (char*)d_ws;
  float*    v_src  = (float*)(ws + OFF_VSRC);
  float*    v_dst  = (float*)(ws + OFF_VDST);
  ushort_t* Pt     = (ushort_t*)(ws + OFF_P);
  float4*   a_pack = (float4*)(ws + OFF_APK);
  int*      cnt    = (int*)(ws + OFF_CNT);
  int*      offs   = (int*)(ws + OFF_OFFS);
  int2*     sorted = (int2*)(ws + OFF_SORT);
  ushort_t* nfb    = (ushort_t*)(ws + OFF_NFB);
  float4*   ahsum  = (float4*)(ws + OFF_AHS);

  float* out_h     = (float*)d_out;                   // [20000,128]
  float* out_alpha = (float*)d_out + (size_t)N_HIGH * D;  // [200000,4]

  k_vp<<<768, 256, 0, stream>>>(Wsrc, Wdst, att_src, att_dst, Whigh,
                                v_src, v_dst, cnt, Pt);
  k_nodehist<<<NP_BLOCKS + H_BLOCKS, 256, 0, stream>>>(
      nf, v_src, v_dst, a_pack, dst, cnt, nfb);
  k_scan<<<1, 1024, 0, stream>>>(cnt, offs);
  k_scatter<<<(N_EDGES + 255) / 256, 256, 0, stream>>>(
      dst, src, offs, cnt, sorted);
  k_ah<<<N_HIGH / 8, 512, 0, stream>>>(a_pack, offs, sorted, ahsum);
  k_mg<<<N_HIGH / 16, 512, 0, stream>>>(nfb, a_pack, ahsum, offs, sorted,
                                        Pt, bhigh, out_alpha, out_h);
}

// Round 19
// 100.283 us; speedup vs baseline: 1.4336x; 1.0480x over previous
//
#include <hip/hip_runtime.h>
#include <math.h>

#define N_NODES 100000
#define N_HIGH  20000
#define N_EDGES 200000
#define D       128
#define HEADS   4
#define EPSF    1e-16f

typedef __attribute__((ext_vector_type(8))) short bf16x8;
typedef __attribute__((ext_vector_type(4))) float f32x4;
typedef unsigned short ushort_t;
typedef unsigned int uint_t;

__device__ __forceinline__ ushort_t bf16_rn(float f) {
  uint_t u = __float_as_uint(f);
  u = u + 0x7FFFu + ((u >> 16) & 1u);   // round-to-nearest-even
  return (ushort_t)(u >> 16);
}
__device__ __forceinline__ uint_t pack_bf2(float x, float y) {
  return (uint_t)bf16_rn(x) | ((uint_t)bf16_rn(y) << 16);
}
__device__ __forceinline__ float readlane_f(float v, int q) {
  return __uint_as_float(__builtin_amdgcn_readlane(__float_as_uint(v), q));
}

// ---------------- workspace layout (bytes) ----------------
constexpr size_t OFF_VSRC = 0;                       // 512 f
constexpr size_t OFF_VDST = OFF_VSRC + 512 * 4;      // 512 f
constexpr size_t OFF_P    = OFF_VDST + 512 * 4;      // Pt bf16 [128][512] (region 256 KB)
constexpr size_t OFF_APK  = OFF_P    + 65536 * 4;    // a_pack float4[200000] = 3.2 MB
constexpr size_t OFF_CNT  = OFF_APK  + 800000 * 4;   // 20000 i
constexpr size_t OFF_OFFS = OFF_CNT  + 20000 * 4;    // 20001 i (padded)
constexpr size_t OFF_FILL = OFF_OFFS + 20004 * 4;    // (unused)
constexpr size_t OFF_SORT = OFF_FILL + 20000 * 4;    // 200000 int2 = 1.6 MB
constexpr size_t OFF_G    = OFF_SORT + 200000 * 8;   // (unused)
constexpr size_t OFF_NFB  = OFF_G    + 20000 * 512 * 2;  // nf bf16 [100000][128] = 25.6 MB

// -------- fused: vecs (+zero cnt) | P  --------
__global__ __launch_bounds__(256) void k_vp(
    const float* __restrict__ Wsrc, const float* __restrict__ Wdst,
    const float* __restrict__ att_src, const float* __restrict__ att_dst,
    const float* __restrict__ Whigh,
    float* __restrict__ v_src, float* __restrict__ v_dst,
    int* __restrict__ cnt, ushort_t* __restrict__ Pt) {
  __shared__ float red[128];
  if (blockIdx.x < 256) {
    int gid = blockIdx.x * 256 + threadIdx.x;
    if (gid < N_HIGH) cnt[gid] = 0;

    int W = blockIdx.x * 4 + (threadIdx.x >> 6);   // 0..1023
    int lane = threadIdx.x & 63;
    int which = W >> 9;
    int idx = W & 511;
    int k = idx >> 2, h = idx & 3;
    const float* wrow = (which ? Wdst : Wsrc) + k * (HEADS * D) + h * D;
    const float* arow = (which ? att_src : att_dst) + h * D;
    float2 wv = ((const float2*)wrow)[lane];
    float2 av = ((const float2*)arow)[lane];
    float s = wv.x * av.x + wv.y * av.y;
#pragma unroll
    for (int o = 32; o; o >>= 1) s += __shfl_xor(s, o);
    if (lane == 0) {
      if (which) v_src[k * HEADS + h] = s;
      else       v_dst[k * HEADS + h] = s;
    }
  } else {
    int hk = blockIdx.x - 256;      // 0..511: (h,col)
    int h = hk >> 7, col = hk & 127;
    int d = threadIdx.x & 127, half = threadIdx.x >> 7;
    const float* ws = Wsrc + col * (HEADS * D) + h * D + half * 64;
    const float* wh = Whigh + (size_t)(half * 64) * D + d;
    float s = 0.f;
#pragma unroll 8
    for (int m = 0; m < 64; ++m) s += ws[m] * wh[(size_t)m * D];
    if (half) red[d] = s;
    __syncthreads();
    if (!half) {
      int kp = (col >> 1) * 8 + h * 2 + (col & 1);
      Pt[(size_t)d * 512 + kp] = bf16_rn(0.25f * (s + red[d]));
    }
  }
}

// -------- fused: nodeproj (+ nf->bf16 copy) | hist --------
#define NP_BLOCKS 1563            // ceil(100000/64)
#define H_BLOCKS  782             // ceil(200000/256)
__global__ __launch_bounds__(256) void k_nodehist(
    const float* __restrict__ nf,
    const float* __restrict__ v_src, const float* __restrict__ v_dst,
    float4* __restrict__ a_pack,
    const int* __restrict__ dst, int* __restrict__ cnt,
    ushort_t* __restrict__ nfb) {
  __shared__ float nfT[128 * 65];
  __shared__ float4 vsf4[128];
  __shared__ float4 vdf4[128];
  __shared__ float part[8][4][64];
  int t = threadIdx.x;
  if (blockIdx.x >= NP_BLOCKS) {
    int e = (blockIdx.x - NP_BLOCKS) * 256 + t;
    if (e < N_EDGES) atomicAdd(&cnt[dst[e]], 1);
    return;
  }
  int n0 = blockIdx.x * 64;

  if (t < 128) vsf4[t] = ((const float4*)v_src)[t];
  else vdf4[t - 128] = ((const float4*)v_dst)[t - 128];

  const float4* nf4 = (const float4*)nf;
#pragma unroll
  for (int j = 0; j < 8; ++j) {
    int f4 = j * 256 + t;
    int r = f4 >> 5, c4 = f4 & 31;
    int n = n0 + r;
    if (n > N_NODES - 1) n = N_NODES - 1;   // clamped dup rows write same bytes
    float4 g = nf4[(size_t)n * 32 + c4];
    nfT[(c4 * 4 + 0) * 65 + r] = g.x;
    nfT[(c4 * 4 + 1) * 65 + r] = g.y;
    nfT[(c4 * 4 + 2) * 65 + r] = g.z;
    nfT[(c4 * 4 + 3) * 65 + r] = g.w;
    ushort4 hb;
    hb.x = bf16_rn(g.x); hb.y = bf16_rn(g.y);
    hb.z = bf16_rn(g.z); hb.w = bf16_rn(g.w);
    ((ushort4*)nfb)[(size_t)n * 32 + c4] = hb;
  }
  __syncthreads();

  int l = t & 63, w = t >> 6;
  float as[4] = {0.f, 0.f, 0.f, 0.f};
  float ad[4] = {0.f, 0.f, 0.f, 0.f};
#pragma unroll 8
  for (int kk = 0; kk < 32; ++kk) {
    int k = w * 32 + kk;
    float x = nfT[k * 65 + l];
    float4 s4 = vsf4[k];
    float4 d4 = vdf4[k];
    as[0] += x * s4.x; as[1] += x * s4.y; as[2] += x * s4.z; as[3] += x * s4.w;
    ad[0] += x * d4.x; ad[1] += x * d4.y; ad[2] += x * d4.z; ad[3] += x * d4.w;
  }
#pragma unroll
  for (int v = 0; v < 4; ++v) {
    part[v][w][l] = as[v];
    part[v + 4][w][l] = ad[v];
  }
  __syncthreads();

  if (t < 64) {
    int ll = t;
    if (n0 + ll < N_NODES) {
      float4 o;
      o.x = part[0][0][ll] + part[0][1][ll] + part[0][2][ll] + part[0][3][ll];
      o.y = part[1][0][ll] + part[1][1][ll] + part[1][2][ll] + part[1][3][ll];
      o.z = part[2][0][ll] + part[2][1][ll] + part[2][2][ll] + part[2][3][ll];
      o.w = part[3][0][ll] + part[3][1][ll] + part[3][2][ll] + part[3][3][ll];
      a_pack[(size_t)(n0 + ll) * 2] = o;
    }
  } else if (t < 128) {
    int ll = t - 64;
    if (n0 + ll < N_NODES) {
      float4 o;
      o.x = part[4][0][ll] + part[4][1][ll] + part[4][2][ll] + part[4][3][ll];
      o.y = part[5][0][ll] + part[5][1][ll] + part[5][2][ll] + part[5][3][ll];
      o.z = part[6][0][ll] + part[6][1][ll] + part[6][2][ll] + part[6][3][ll];
      o.w = part[7][0][ll] + part[7][1][ll] + part[7][2][ll] + part[7][3][ll];
      a_pack[(size_t)(n0 + ll) * 2 + 1] = o;
    }
  }
}

// exclusive scan of cnt[20000] -> offs[20001]; shfl-based, ONE barrier
#define SCAN_PER 20
__global__ __launch_bounds__(1024) void k_scan(
    const int* __restrict__ cnt, int* __restrict__ offs) {
  __shared__ int wsum[16];
  int t = threadIdx.x;
  int lane = t & 63, wv = t >> 6;
  int base = t * SCAN_PER;
  int loc[SCAN_PER];
  int s = 0;
#pragma unroll
  for (int i = 0; i < SCAN_PER; ++i) {
    int idx = base + i;
    loc[i] = (idx < N_HIGH) ? cnt[idx] : 0;
    s += loc[i];
  }
  int tot = s;
#pragma unroll
  for (int o = 1; o < 64; o <<= 1) {
    int v = __shfl_up(tot, o);
    if (lane >= o) tot += v;
  }
  if (lane == 63) wsum[wv] = tot;
  __syncthreads();
  int wpre = 0;
  for (int i = 0; i < 16; ++i) wpre += (i < wv) ? wsum[i] : 0;
  int run = wpre + tot - s;
#pragma unroll
  for (int i = 0; i < SCAN_PER; ++i) {
    int idx = base + i;
    if (idx < N_HIGH) {
      offs[idx] = run;
      run += loc[i];
    }
  }
  if (t == 1023) offs[N_HIGH] = wpre + tot;
}

// counting-sort scatter: slot via atomicSub on cnt (no fill array)
__global__ void k_scatter(const int* __restrict__ dst, const int* __restrict__ src,
                          const int* __restrict__ offs,
                          int* __restrict__ cnt, int2* __restrict__ sorted) {
  int e = blockIdx.x * blockDim.x + threadIdx.x;
  if (e < N_EDGES) {
    int d = dst[e];
    int pos = offs[d] + (atomicSub(&cnt[d], 1) - 1);
    sorted[pos] = make_int2(e, src[e]);
  }
}

// -------- fused main+gemm: 512 thr = 8 waves; 16 hyperedges (2/wave) --------
// Per-wave schedule: load sorted -> ISSUE chunk-0 nfb gathers + a_pack loads
// together -> shuffle-reduce mean (loads in flight) -> softmax -> FMA chunk 0
// (data landed) -> remaining chunks. One serial latency round fewer than
// r18 + no separate k_ah kernel.
#define RS 520   // padded LDS row stride (ushorts): 2-way-free ds_read_b128
__global__ __launch_bounds__(512) void k_mg(
    const ushort_t* __restrict__ nfb,
    const float4* __restrict__ a_pack,
    const int* __restrict__ offs, const int2* __restrict__ sorted,
    const ushort_t* __restrict__ Pt, const float* __restrict__ b,
    float* __restrict__ alpha_out, float* __restrict__ out) {
  __shared__ ushort_t Gl[16 * RS];          // 16.3 KB
  int t = threadIdx.x;
  int w = t >> 6, lane = t & 63;
  int j0 = blockIdx.x * 16;
  int rowA = w * 2, rowB = rowA + 1;
  int jA = j0 + rowA;
  int oA0 = offs[jA], oA1 = offs[jA + 1], oB1 = offs[jA + 2];
  int oB0 = oA1;
  int degA = oA1 - oA0, degB = oB1 - oB0;

  float2 accA[4], accB[4];
#pragma unroll
  for (int h = 0; h < 4; ++h) {
    accA[h] = make_float2(0.f, 0.f);
    accB[h] = make_float2(0.f, 0.f);
  }

  if (degA <= 64 && degB <= 64) {
    // ---- interleaved fast path (handles deg==0 via act masks) ----
    bool actA = lane < degA, actB = lane < degB;
    int idxA = min(oA0 + (actA ? lane : 0), N_EDGES - 1);
    int idxB = min(oB0 + (actB ? lane : 0), N_EDGES - 1);
    int2 esA = sorted[idxA];
    int2 esB = sorted[idxB];
    int eA = esA.x, srA = esA.y;
    int eB = esB.x, srB = esB.y;

    // issue chunk-0 nfb gathers IMMEDIATELY (independent of softmax)
    const uint_t* __restrict__ nfbu = (const uint_t*)nfb;
    uint_t xa0[8], xb0[8];
#pragma unroll
    for (int i = 0; i < 8; ++i) {
      int sqA = __builtin_amdgcn_readlane(srA, i);
      int sqB = __builtin_amdgcn_readlane(srB, i);
      xa0[i] = nfbu[(size_t)sqA * 64 + lane];
      xb0[i] = nfbu[(size_t)sqB * 64 + lane];
    }
    // a_pack loads (mean source + dst term), concurrent with above
    float4 z4 = make_float4(0.f, 0.f, 0.f, 0.f);
    float4 asA = z4, adA = z4, asB = z4, adB = z4;
    if (actA) { asA = a_pack[(size_t)srA * 2]; adA = a_pack[(size_t)srA * 2 + 1]; }
    if (actB) { asB = a_pack[(size_t)srB * 2]; adB = a_pack[(size_t)srB * 2 + 1]; }

    // mean reduce (overlaps with in-flight nfb gathers)
    float sA[4] = {asA.x, asA.y, asA.z, asA.w};
    float sB[4] = {asB.x, asB.y, asB.z, asB.w};
#pragma unroll
    for (int o = 32; o; o >>= 1)
#pragma unroll
      for (int h = 0; h < 4; ++h) {
        sA[h] += __shfl_xor(sA[h], o);
        sB[h] += __shfl_xor(sB[h], o);
      }
    float invA = 1.0f / (float)max(degA, 1);
    float invB = 1.0f / (float)max(degB, 1);
    float exA[4], exB[4];
    {
      float pA0 = sA[0] * invA + adA.x, pA1 = sA[1] * invA + adA.y;
      float pA2 = sA[2] * invA + adA.z, pA3 = sA[3] * invA + adA.w;
      float pB0 = sB[0] * invB + adB.x, pB1 = sB[1] * invB + adB.y;
      float pB2 = sB[2] * invB + adB.z, pB3 = sB[3] * invB + adB.w;
      pA0 = pA0 >= 0.f ? pA0 : 0.2f * pA0;
      pA1 = pA1 >= 0.f ? pA1 : 0.2f * pA1;
      pA2 = pA2 >= 0.f ? pA2 : 0.2f * pA2;
      pA3 = pA3 >= 0.f ? pA3 : 0.2f * pA3;
      pB0 = pB0 >= 0.f ? pB0 : 0.2f * pB0;
      pB1 = pB1 >= 0.f ? pB1 : 0.2f * pB1;
      pB2 = pB2 >= 0.f ? pB2 : 0.2f * pB2;
      pB3 = pB3 >= 0.f ? pB3 : 0.2f * pB3;
      exA[0] = actA ? expf(pA0) : 0.f;
      exA[1] = actA ? expf(pA1) : 0.f;
      exA[2] = actA ? expf(pA2) : 0.f;
      exA[3] = actA ? expf(pA3) : 0.f;
      exB[0] = actB ? expf(pB0) : 0.f;
      exB[1] = actB ? expf(pB1) : 0.f;
      exB[2] = actB ? expf(pB2) : 0.f;
      exB[3] = actB ? expf(pB3) : 0.f;
    }
    float seA[4] = {exA[0], exA[1], exA[2], exA[3]};
    float seB[4] = {exB[0], exB[1], exB[2], exB[3]};
#pragma unroll
    for (int o = 32; o; o >>= 1)
#pragma unroll
      for (int h = 0; h < 4; ++h) {
        seA[h] += __shfl_xor(seA[h], o);
        seB[h] += __shfl_xor(seB[h], o);
      }
    float alA[4], alB[4];
#pragma unroll
    for (int h = 0; h < 4; ++h) {
      alA[h] = exA[h] / (seA[h] + EPSF);
      alB[h] = exB[h] / (seB[h] + EPSF);
    }
    if (actA)
      ((float4*)alpha_out)[eA] = make_float4(alA[0], alA[1], alA[2], alA[3]);
    if (actB)
      ((float4*)alpha_out)[eB] = make_float4(alB[0], alB[1], alB[2], alB[3]);

    // FMA chunk 0 (loads issued before softmax; pads contribute 0)
#pragma unroll
    for (int i = 0; i < 8; ++i) {
      float a0 = readlane_f(alA[0], i);
      float a1 = readlane_f(alA[1], i);
      float a2 = readlane_f(alA[2], i);
      float a3 = readlane_f(alA[3], i);
      float b0 = readlane_f(alB[0], i);
      float b1 = readlane_f(alB[1], i);
      float b2 = readlane_f(alB[2], i);
      float b3 = readlane_f(alB[3], i);
      float xAx = __uint_as_float(xa0[i] << 16);
      float xAy = __uint_as_float(xa0[i] & 0xFFFF0000u);
      float xBx = __uint_as_float(xb0[i] << 16);
      float xBy = __uint_as_float(xb0[i] & 0xFFFF0000u);
      accA[0].x += a0 * xAx; accA[0].y += a0 * xAy;
      accA[1].x += a1 * xAx; accA[1].y += a1 * xAy;
      accA[2].x += a2 * xAx; accA[2].y += a2 * xAy;
      accA[3].x += a3 * xAx; accA[3].y += a3 * xAy;
      accB[0].x += b0 * xBx; accB[0].y += b0 * xBy;
      accB[1].x += b1 * xBx; accB[1].y += b1 * xBy;
      accB[2].x += b2 * xBx; accB[2].y += b2 * xBy;
      accB[3].x += b3 * xBx; accB[3].y += b3 * xBy;
    }
    // remaining chunks
    int dmax8 = (max(degA, degB) + 7) & ~7;
    for (int c0 = 8; c0 < dmax8; c0 += 8) {
      uint_t xa[8], xb[8];
#pragma unroll
      for (int i = 0; i < 8; ++i) {
        int sqA = __builtin_amdgcn_readlane(srA, c0 + i);
        int sqB = __builtin_amdgcn_readlane(srB, c0 + i);
        xa[i] = nfbu[(size_t)sqA * 64 + lane];
        xb[i] = nfbu[(size_t)sqB * 64 + lane];
      }
#pragma unroll
      for (int i = 0; i < 8; ++i) {
        int q = c0 + i;
        float a0 = readlane_f(alA[0], q);
        float a1 = readlane_f(alA[1], q);
        float a2 = readlane_f(alA[2], q);
        float a3 = readlane_f(alA[3], q);
        float b0 = readlane_f(alB[0], q);
        float b1 = readlane_f(alB[1], q);
        float b2 = readlane_f(alB[2], q);
        float b3 = readlane_f(alB[3], q);
        float xAx = __uint_as_float(xa[i] << 16);
        float xAy = __uint_as_float(xa[i] & 0xFFFF0000u);
        float xBx = __uint_as_float(xb[i] << 16);
        float xBy = __uint_as_float(xb[i] & 0xFFFF0000u);
        accA[0].x += a0 * xAx; accA[0].y += a0 * xAy;
        accA[1].x += a1 * xAx; accA[1].y += a1 * xAy;
        accA[2].x += a2 * xAx; accA[2].y += a2 * xAy;
        accA[3].x += a3 * xAx; accA[3].y += a3 * xAy;
        accB[0].x += b0 * xBx; accB[0].y += b0 * xBy;
        accB[1].x += b1 * xBx; accB[1].y += b1 * xBy;
        accB[2].x += b2 * xBx; accB[2].y += b2 * xBy;
        accB[3].x += b3 * xBx; accB[3].y += b3 * xBy;
      }
    }
  } else {
    // ---- rare fallback: general chunked path, works for any deg ----
    for (int pick = 0; pick < 2; ++pick) {
      int o0 = pick ? oB0 : oA0;
      int deg = pick ? degB : degA;
      float2* acc = pick ? accB : accA;

      float s[4] = {0.f, 0.f, 0.f, 0.f};
      for (int i = lane; i < deg; i += 64) {
        int2 es = sorted[o0 + i];
        float4 a = a_pack[(size_t)es.y * 2];
        s[0] += a.x; s[1] += a.y; s[2] += a.z; s[3] += a.w;
      }
#pragma unroll
      for (int o = 32; o; o >>= 1)
#pragma unroll
        for (int h = 0; h < 4; ++h) s[h] += __shfl_xor(s[h], o);
      float ah[4];
      float invdeg = 1.0f / (float)max(deg, 1);
#pragma unroll
      for (int h = 0; h < 4; ++h) ah[h] = s[h] * invdeg;

      float se[4] = {0.f, 0.f, 0.f, 0.f};
      for (int i = lane; i < deg; i += 64) {
        int2 es = sorted[o0 + i];
        float4 a = a_pack[(size_t)es.y * 2 + 1];
        float p[4] = {ah[0] + a.x, ah[1] + a.y, ah[2] + a.z, ah[3] + a.w};
#pragma unroll
        for (int h = 0; h < 4; ++h) {
          float pp = p[h] >= 0.f ? p[h] : 0.2f * p[h];
          se[h] += expf(pp);
        }
      }
#pragma unroll
      for (int o = 32; o; o >>= 1)
#pragma unroll
        for (int h = 0; h < 4; ++h) se[h] += __shfl_xor(se[h], o);
      float inv[4];
#pragma unroll
      for (int h = 0; h < 4; ++h) inv[h] = 1.0f / (se[h] + EPSF);

      for (int c0 = 0; c0 < deg; c0 += 64) {
        int i = c0 + lane;
        float al[4] = {0.f, 0.f, 0.f, 0.f};
        int sreg = 0;
        if (i < deg) {
          int2 es = sorted[o0 + i];
          sreg = es.y;
          float4 a = a_pack[(size_t)sreg * 2 + 1];
          float p[4] = {ah[0] + a.x, ah[1] + a.y, ah[2] + a.z, ah[3] + a.w};
#pragma unroll
          for (int h = 0; h < 4; ++h) {
            float pp = p[h] >= 0.f ? p[h] : 0.2f * p[h];
            al[h] = expf(pp) * inv[h];
          }
          ((float4*)alpha_out)[es.x] = make_float4(al[0], al[1], al[2], al[3]);
        }
        int cl = min(64, deg - c0);
#pragma unroll 2
        for (int q = 0; q < cl; ++q) {
          int sq = __builtin_amdgcn_readlane(sreg, q);
          float a0 = readlane_f(al[0], q);
          float a1 = readlane_f(al[1], q);
          float a2 = readlane_f(al[2], q);
          float a3 = readlane_f(al[3], q);
          uint_t xw = ((const uint_t*)nfb)[(size_t)sq * 64 + lane];
          float xx = __uint_as_float(xw << 16);
          float xy = __uint_as_float(xw & 0xFFFF0000u);
          acc[0].x += a0 * xx; acc[0].y += a0 * xy;
          acc[1].x += a1 * xx; acc[1].y += a1 * xy;
          acc[2].x += a2 * xx; acc[2].y += a2 * xy;
          acc[3].x += a3 * xx; acc[3].y += a3 * xy;
        }
      }
    }
  }
  // G rows to LDS, k = lane*8 + h*2 + b (matches Pt perm)
  uint4 gwA, gwB;
  gwA.x = pack_bf2(accA[0].x, accA[0].y);
  gwA.y = pack_bf2(accA[1].x, accA[1].y);
  gwA.z = pack_bf2(accA[2].x, accA[2].y);
  gwA.w = pack_bf2(accA[3].x, accA[3].y);
  gwB.x = pack_bf2(accB[0].x, accB[0].y);
  gwB.y = pack_bf2(accB[1].x, accB[1].y);
  gwB.z = pack_bf2(accB[2].x, accB[2].y);
  gwB.w = pack_bf2(accB[3].x, accB[3].y);
  *(uint4*)&Gl[rowA * RS + lane * 8] = gwA;
  *(uint4*)&Gl[rowB * RS + lane * 8] = gwB;
  __syncthreads();

  // GEMM phase: wave w owns column tile nt = w (16 cols)
  int lr = lane & 15, lg = lane >> 4;
  f32x4 c0v = (f32x4){0.f, 0.f, 0.f, 0.f};
  const ushort_t* Pa = Pt + (size_t)lr * 512 + lg * 8 + (size_t)w * 16 * 512;
#pragma unroll
  for (int kt = 0; kt < 16; ++kt) {
    bf16x8 a = *(const bf16x8*)&Gl[lr * RS + kt * 32 + lg * 8];
    bf16x8 b0 = *(const bf16x8*)(Pa + kt * 32);
    c0v = __builtin_amdgcn_mfma_f32_16x16x32_bf16(a, b0, c0v, 0, 0, 0);
  }
  int col0 = w * 16 + lr;
  float bb0 = b[col0];
#pragma unroll
  for (int r = 0; r < 4; ++r) {
    int row = j0 + lg * 4 + r;
    out[(size_t)row * 128 + col0] = c0v[r] + bb0;
  }
}

extern "C" void kernel_launch(void* const* d_in, const int* in_sizes, int n_in,
                              void* d_out, int out_size, void* d_ws, size_t ws_size,
                              hipStream_t stream) {
  const float* nf      = (const float*)d_in[0];
  const float* Wsrc    = (const float*)d_in[1];
  const float* Wdst    = (const float*)d_in[2];
  const float* att_src = (const float*)d_in[3];
  const float* att_dst = (const float*)d_in[4];
  const float* Whigh   = (const float*)d_in[5];
  const float* bhigh   = (const float*)d_in[6];
  const int*   src     = (const int*)d_in[7];
  const int*   dst     = (const int*)d_in[8];

  char* ws = (char*)d_ws;
  float*    v_src  = (float*)(ws + OFF_VSRC);
  float*    v_dst  = (float*)(ws + OFF_VDST);
  ushort_t* Pt     = (ushort_t*)(ws + OFF_P);
  float4*   a_pack = (float4*)(ws + OFF_APK);
  int*      cnt    = (int*)(ws + OFF_CNT);
  int*      offs   = (int*)(ws + OFF_OFFS);
  int2*     sorted = (int2*)(ws + OFF_SORT);
  ushort_t* nfb    = (ushort_t*)(ws + OFF_NFB);

  float* out_h     = (float*)d_out;                   // [20000,128]
  float* out_alpha = (float*)d_out + (size_t)N_HIGH * D;  // [200000,4]

  k_vp<<<768, 256, 0, stream>>>(Wsrc, Wdst, att_src, att_dst, Whigh,
                                v_src, v_dst, cnt, Pt);
  k_nodehist<<<NP_BLOCKS + H_BLOCKS, 256, 0, stream>>>(
      nf, v_src, v_dst, a_pack, dst, cnt, nfb);
  k_scan<<<1, 1024, 0, stream>>>(cnt, offs);
  k_scatter<<<(N_EDGES + 255) / 256, 256, 0, stream>>>(
      dst, src, offs, cnt, sorted);
  k_mg<<<N_HIGH / 16, 512, 0, stream>>>(nfb, a_pack, offs, sorted,
                                        Pt, bhigh, out_alpha, out_h);
}